// Round 1
// baseline (922.589 us; speedup 1.0000x reference)
//
#include <hip/hip_runtime.h>
#include <hip/hip_bf16.h>

// Problem dims (hardcoded): B=2, N=512, C=768, H=16, D=48, CS=384, CZ=128
#define NB 2
#define NN 512
#define CC 768
#define NH 16
#define DD 48
#define CS 384
#define CZ 128

__device__ inline float2 wave_reduce_sum2(float s, float q) {
  #pragma unroll
  for (int off = 32; off > 0; off >>= 1) {
    s += __shfl_xor(s, off);
    q += __shfl_xor(q, off);
  }
  return make_float2(s, q);
}

__device__ inline float sigmoidf_(float x) { return 1.f / (1.f + __expf(-x)); }

// ---------------------------------------------------------------------------
// K1: LN(a_i) -> aln (no affine), LN(s_i)*w -> sln (weight only)
// grid = B*N = 1024 blocks, 256 threads
// ---------------------------------------------------------------------------
__global__ __launch_bounds__(256) void k_ln(
    const float* __restrict__ a_i, const float* __restrict__ s_i,
    const float* __restrict__ ln2w,
    float* __restrict__ aln, float* __restrict__ sln) {
  int r = blockIdx.x, t = threadIdx.x;
  int lane = t & 63, w = t >> 6;
  __shared__ float red[2][4];

  // ---- a row (768) ----
  const float* ar = a_i + (size_t)r * CC;
  float x0 = ar[t], x1 = ar[t + 256], x2 = ar[t + 512];
  float s = x0 + x1 + x2, sq = x0 * x0 + x1 * x1 + x2 * x2;
  float2 rs = wave_reduce_sum2(s, sq);
  if (lane == 0) { red[0][w] = rs.x; red[1][w] = rs.y; }
  __syncthreads();
  float S = red[0][0] + red[0][1] + red[0][2] + red[0][3];
  float SQ = red[1][0] + red[1][1] + red[1][2] + red[1][3];
  float mean = S * (1.f / CC);
  float var = SQ * (1.f / CC) - mean * mean;
  float rstd = rsqrtf(var + 1e-5f);
  float* alr = aln + (size_t)r * CC;
  alr[t] = (x0 - mean) * rstd;
  alr[t + 256] = (x1 - mean) * rstd;
  alr[t + 512] = (x2 - mean) * rstd;

  // ---- s row (384) ----
  const float* sr = s_i + (size_t)r * CS;
  float y0 = sr[t];
  float y1 = (t < 128) ? sr[256 + t] : 0.f;
  float s2 = y0 + y1, sq2 = y0 * y0 + y1 * y1;
  float2 rs2 = wave_reduce_sum2(s2, sq2);
  __syncthreads();  // protect red[] reads above
  if (lane == 0) { red[0][w] = rs2.x; red[1][w] = rs2.y; }
  __syncthreads();
  float S2 = red[0][0] + red[0][1] + red[0][2] + red[0][3];
  float SQ2 = red[1][0] + red[1][1] + red[1][2] + red[1][3];
  float mean2 = S2 * (1.f / CS);
  float var2 = SQ2 * (1.f / CS) - mean2 * mean2;
  float rstd2 = rsqrtf(var2 + 1e-5f);
  float* slr = sln + (size_t)r * CS;
  slr[t] = (y0 - mean2) * rstd2 * ln2w[t];
  if (t < 128) slr[256 + t] = (y1 - mean2) * rstd2 * ln2w[256 + t];
}

// ---------------------------------------------------------------------------
// K2: acond = sigmoid(sln@Wl^T + bl) * aln + sln@Wnb^T
// M=1024, N=768, K=384. grid (12,16), 256 thr, 64x64 tile, 4x4 micro.
// ---------------------------------------------------------------------------
__global__ __launch_bounds__(256) void k_adaln(
    const float* __restrict__ sln, const float* __restrict__ aln,
    const float* __restrict__ Wl, const float* __restrict__ bl,
    const float* __restrict__ Wnb, float* __restrict__ acond) {
  __shared__ float As[16][65], B1[16][65], B2[16][65];
  int cb = blockIdx.x * 64, rb = blockIdx.y * 64;
  int t = threadIdx.x, tr = t >> 4, tc = t & 15;
  int lk = t & 15, lr = t >> 4;
  float acc1[4][4] = {}, acc2[4][4] = {};
  for (int kb = 0; kb < CS; kb += 16) {
    #pragma unroll
    for (int i = 0; i < 4; ++i) {
      int row = lr + i * 16;
      As[lk][row] = sln[(size_t)(rb + row) * CS + kb + lk];
      B1[lk][row] = Wl[(size_t)(cb + row) * CS + kb + lk];
      B2[lk][row] = Wnb[(size_t)(cb + row) * CS + kb + lk];
    }
    __syncthreads();
    #pragma unroll
    for (int k = 0; k < 16; ++k) {
      float a[4], b1[4], b2[4];
      #pragma unroll
      for (int i = 0; i < 4; ++i) a[i] = As[k][tr * 4 + i];
      #pragma unroll
      for (int j = 0; j < 4; ++j) { b1[j] = B1[k][tc * 4 + j]; b2[j] = B2[k][tc * 4 + j]; }
      #pragma unroll
      for (int i = 0; i < 4; ++i)
        #pragma unroll
        for (int j = 0; j < 4; ++j) {
          acc1[i][j] += a[i] * b1[j];
          acc2[i][j] += a[i] * b2[j];
        }
    }
    __syncthreads();
  }
  #pragma unroll
  for (int i = 0; i < 4; ++i) {
    int r = rb + tr * 4 + i;
    #pragma unroll
    for (int j = 0; j < 4; ++j) {
      int c = cb + tc * 4 + j;
      float sig = sigmoidf_(acc1[i][j] + bl[c]);
      acond[(size_t)r * CC + c] = sig * aln[(size_t)r * CC + c] + acc2[i][j];
    }
  }
}

// ---------------------------------------------------------------------------
// K3: fused QKVG: q=(acond@Wq^T+bq)/sqrt(D), k, v, g=sigmoid(acond@Wg^T)
// M=1024, N=768, K=768. grid (12,16), 256 thr.
// ---------------------------------------------------------------------------
__global__ __launch_bounds__(256) void k_qkvg(
    const float* __restrict__ acond,
    const float* __restrict__ Wq, const float* __restrict__ bq,
    const float* __restrict__ Wk, const float* __restrict__ Wv,
    const float* __restrict__ Wg,
    float* __restrict__ qo, float* __restrict__ ko,
    float* __restrict__ vo, float* __restrict__ go) {
  __shared__ float As[16][65], Bq[16][65], Bk[16][65], Bv[16][65], Bg[16][65];
  int cb = blockIdx.x * 64, rb = blockIdx.y * 64;
  int t = threadIdx.x, tr = t >> 4, tc = t & 15;
  int lk = t & 15, lr = t >> 4;
  float aq[4][4] = {}, ak[4][4] = {}, av[4][4] = {}, ag[4][4] = {};
  for (int kb = 0; kb < CC; kb += 16) {
    #pragma unroll
    for (int i = 0; i < 4; ++i) {
      int row = lr + i * 16;
      As[lk][row] = acond[(size_t)(rb + row) * CC + kb + lk];
      Bq[lk][row] = Wq[(size_t)(cb + row) * CC + kb + lk];
      Bk[lk][row] = Wk[(size_t)(cb + row) * CC + kb + lk];
      Bv[lk][row] = Wv[(size_t)(cb + row) * CC + kb + lk];
      Bg[lk][row] = Wg[(size_t)(cb + row) * CC + kb + lk];
    }
    __syncthreads();
    #pragma unroll
    for (int k = 0; k < 16; ++k) {
      float a[4], bqv[4], bkv[4], bvv[4], bgv[4];
      #pragma unroll
      for (int i = 0; i < 4; ++i) a[i] = As[k][tr * 4 + i];
      #pragma unroll
      for (int j = 0; j < 4; ++j) {
        bqv[j] = Bq[k][tc * 4 + j]; bkv[j] = Bk[k][tc * 4 + j];
        bvv[j] = Bv[k][tc * 4 + j]; bgv[j] = Bg[k][tc * 4 + j];
      }
      #pragma unroll
      for (int i = 0; i < 4; ++i)
        #pragma unroll
        for (int j = 0; j < 4; ++j) {
          aq[i][j] += a[i] * bqv[j];
          ak[i][j] += a[i] * bkv[j];
          av[i][j] += a[i] * bvv[j];
          ag[i][j] += a[i] * bgv[j];
        }
    }
    __syncthreads();
  }
  const float qscale = 0.14433756729740643f;  // 1/sqrt(48)
  #pragma unroll
  for (int i = 0; i < 4; ++i) {
    int r = rb + tr * 4 + i;
    #pragma unroll
    for (int j = 0; j < 4; ++j) {
      int c = cb + tc * 4 + j;
      size_t o = (size_t)r * CC + c;
      qo[o] = (aq[i][j] + bq[c]) * qscale;
      ko[o] = ak[i][j];
      vo[o] = av[i][j];
      go[o] = sigmoidf_(ag[i][j]);
    }
  }
}

// ---------------------------------------------------------------------------
// K4: pair bias: bias[b,h,i,j] = LN(z[b,i,j,:])@Wz[h,:] + beta[b,i,j]
// grid = B*N*(N/32) = 16384 blocks, 256 thr (4 waves, wave per z-row)
// ---------------------------------------------------------------------------
__global__ __launch_bounds__(256) void k_pairbias(
    const float* __restrict__ z, const float* __restrict__ beta,
    const float* __restrict__ lnzw, const float* __restrict__ lnzb,
    const float* __restrict__ Wz, float* __restrict__ bias) {
  __shared__ __align__(16) float zn[32][130];
  __shared__ __align__(16) float WzS[16][130];
  int blk = blockIdx.x;
  int jt = blk & 15, i = (blk >> 4) & 511, b = blk >> 13;
  int jbase = jt * 32;
  int t = threadIdx.x, lane = t & 63, w = t >> 6;

  for (int idx = t; idx < NH * CZ; idx += 256)
    WzS[idx >> 7][idx & 127] = Wz[idx];

  float w0 = lnzw[lane * 2], w1 = lnzw[lane * 2 + 1];
  float b0 = lnzb[lane * 2], b1 = lnzb[lane * 2 + 1];
  const float* zrow = z + ((size_t)(b * NN + i) * NN + jbase) * CZ;
  #pragma unroll
  for (int it = 0; it < 8; ++it) {
    int j = w * 8 + it;
    float2 zv = *(const float2*)(zrow + (size_t)j * CZ + lane * 2);
    float s = zv.x + zv.y, sq = zv.x * zv.x + zv.y * zv.y;
    float2 rs = wave_reduce_sum2(s, sq);
    float mean = rs.x * (1.f / CZ);
    float var = rs.y * (1.f / CZ) - mean * mean;
    float rstd = rsqrtf(var + 1e-5f);
    float n0 = (zv.x - mean) * rstd * w0 + b0;
    float n1 = (zv.y - mean) * rstd * w1 + b1;
    *(float2*)&zn[j][lane * 2] = make_float2(n0, n1);
  }
  __syncthreads();
  #pragma unroll
  for (int p = 0; p < 2; ++p) {
    int h = p * 8 + (t >> 5), j = t & 31;
    float acc = 0.f;
    const float2* zr = (const float2*)&zn[j][0];
    const float2* wr = (const float2*)&WzS[h][0];
    #pragma unroll
    for (int k2 = 0; k2 < 64; ++k2) {
      float2 a = zr[k2], wv = wr[k2];
      acc += a.x * wv.x + a.y * wv.y;
    }
    bias[(((size_t)b * NH + h) * NN + i) * NN + jbase + j] =
        acc + beta[((size_t)b * NN + i) * NN + jbase + j];
  }
}

// ---------------------------------------------------------------------------
// K5: flash attention + g-gating. block per (b,h,32-row q tile). 256 thr.
// go_out[b,i,h*48+d] = g * sum_j softmax(q.k + bias) v
// ---------------------------------------------------------------------------
__global__ __launch_bounds__(256) void k_attn(
    const float* __restrict__ q, const float* __restrict__ k,
    const float* __restrict__ v, const float* __restrict__ g,
    const float* __restrict__ bias, float* __restrict__ go_out) {
  __shared__ __align__(16) float qs[32][49];
  __shared__ __align__(16) float ks[64][49];
  __shared__ __align__(16) float vs[64][49];
  __shared__ __align__(16) float ps[32][65];
  __shared__ __align__(16) float bs[32][65];
  __shared__ float mrow[32], lrow[32], crow[32];
  int blk = blockIdx.x;
  int it = blk & 15, h = (blk >> 4) & 15, b = blk >> 8;
  int ibase = it * 32;
  int t = threadIdx.x;
  int tr = t >> 4, tc = t & 15;  // scores: qi=tr*2+i, ji=tc*4+j
  int td = t & 15;               // pv: qi=tr*2+i, d=td*3+dd

  for (int idx = t; idx < 32 * 48; idx += 256) {
    int r = idx / 48, c = idx % 48;
    qs[r][c] = q[((size_t)(b * NN) + ibase + r) * CC + h * DD + c];
  }
  if (t < 32) { mrow[t] = -1e30f; lrow[t] = 0.f; }
  float acc[2][3] = {};
  const size_t bh = (size_t)b * NH + h;

  for (int jb = 0; jb < NN; jb += 64) {
    __syncthreads();
    for (int idx = t; idx < 64 * 48; idx += 256) {
      int r = idx / 48, c = idx % 48;
      size_t src = ((size_t)(b * NN) + jb + r) * CC + h * DD + c;
      ks[r][c] = k[src];
      vs[r][c] = v[src];
    }
    for (int idx = t; idx < 32 * 64; idx += 256) {
      int r = idx >> 6, c = idx & 63;
      bs[r][c] = bias[(bh * NN + ibase + r) * NN + jb + c];
    }
    __syncthreads();
    // scores
    float sc[2][4] = {};
    #pragma unroll
    for (int d = 0; d < DD; ++d) {
      float a0 = qs[tr * 2][d], a1 = qs[tr * 2 + 1][d];
      #pragma unroll
      for (int j = 0; j < 4; ++j) {
        float bk = ks[tc * 4 + j][d];
        sc[0][j] += a0 * bk;
        sc[1][j] += a1 * bk;
      }
    }
    #pragma unroll
    for (int i = 0; i < 2; ++i)
      #pragma unroll
      for (int j = 0; j < 4; ++j)
        ps[tr * 2 + i][tc * 4 + j] = sc[i][j] + bs[tr * 2 + i][tc * 4 + j];
    __syncthreads();
    // online softmax (rows)
    if (t < 32) {
      float m = mrow[t], rmax = m;
      #pragma unroll
      for (int j = 0; j < 64; ++j) rmax = fmaxf(rmax, ps[t][j]);
      float corr = __expf(m - rmax);
      float sum = 0.f;
      #pragma unroll
      for (int j = 0; j < 64; ++j) {
        float p = __expf(ps[t][j] - rmax);
        ps[t][j] = p;
        sum += p;
      }
      lrow[t] = lrow[t] * corr + sum;
      mrow[t] = rmax;
      crow[t] = corr;
    }
    __syncthreads();
    // PV
    float c0 = crow[tr * 2], c1 = crow[tr * 2 + 1];
    #pragma unroll
    for (int dd = 0; dd < 3; ++dd) { acc[0][dd] *= c0; acc[1][dd] *= c1; }
    #pragma unroll
    for (int ji = 0; ji < 64; ++ji) {
      float p0 = ps[tr * 2][ji], p1 = ps[tr * 2 + 1][ji];
      #pragma unroll
      for (int dd = 0; dd < 3; ++dd) {
        float vv = vs[ji][td * 3 + dd];
        acc[0][dd] += p0 * vv;
        acc[1][dd] += p1 * vv;
      }
    }
  }
  __syncthreads();
  #pragma unroll
  for (int i = 0; i < 2; ++i) {
    int qi = tr * 2 + i;
    float inv = 1.f / lrow[qi];
    #pragma unroll
    for (int dd = 0; dd < 3; ++dd) {
      int d = td * 3 + dd;
      size_t o = ((size_t)(b * NN) + ibase + qi) * CC + h * DD + d;
      go_out[o] = acc[i][dd] * inv * g[o];
    }
  }
}

// ---------------------------------------------------------------------------
// K6: out = sigmoid(s_i@Wgs^T + bgs) * (go@Wo^T)
// grid (12,16), 256 thr.
// ---------------------------------------------------------------------------
__global__ __launch_bounds__(256) void k_out(
    const float* __restrict__ go, const float* __restrict__ Wo,
    const float* __restrict__ s_i, const float* __restrict__ Wgs,
    const float* __restrict__ bgs, float* __restrict__ out) {
  __shared__ float As[16][65], Bs[16][65];
  int cb = blockIdx.x * 64, rb = blockIdx.y * 64;
  int t = threadIdx.x, tr = t >> 4, tc = t & 15;
  int lk = t & 15, lr = t >> 4;
  float acc1[4][4] = {}, acc2[4][4] = {};
  for (int kb = 0; kb < CC; kb += 16) {
    #pragma unroll
    for (int i = 0; i < 4; ++i) {
      int row = lr + i * 16;
      As[lk][row] = go[(size_t)(rb + row) * CC + kb + lk];
      Bs[lk][row] = Wo[(size_t)(cb + row) * CC + kb + lk];
    }
    __syncthreads();
    #pragma unroll
    for (int k = 0; k < 16; ++k) {
      float a[4], bb[4];
      #pragma unroll
      for (int i = 0; i < 4; ++i) a[i] = As[k][tr * 4 + i];
      #pragma unroll
      for (int j = 0; j < 4; ++j) bb[j] = Bs[k][tc * 4 + j];
      #pragma unroll
      for (int i = 0; i < 4; ++i)
        #pragma unroll
        for (int j = 0; j < 4; ++j) acc1[i][j] += a[i] * bb[j];
    }
    __syncthreads();
  }
  for (int kb = 0; kb < CS; kb += 16) {
    #pragma unroll
    for (int i = 0; i < 4; ++i) {
      int row = lr + i * 16;
      As[lk][row] = s_i[(size_t)(rb + row) * CS + kb + lk];
      Bs[lk][row] = Wgs[(size_t)(cb + row) * CS + kb + lk];
    }
    __syncthreads();
    #pragma unroll
    for (int k = 0; k < 16; ++k) {
      float a[4], bb[4];
      #pragma unroll
      for (int i = 0; i < 4; ++i) a[i] = As[k][tr * 4 + i];
      #pragma unroll
      for (int j = 0; j < 4; ++j) bb[j] = Bs[k][tc * 4 + j];
      #pragma unroll
      for (int i = 0; i < 4; ++i)
        #pragma unroll
        for (int j = 0; j < 4; ++j) acc2[i][j] += a[i] * bb[j];
    }
    __syncthreads();
  }
  #pragma unroll
  for (int i = 0; i < 4; ++i) {
    int r = rb + tr * 4 + i;
    #pragma unroll
    for (int j = 0; j < 4; ++j) {
      int c = cb + tc * 4 + j;
      float gate = sigmoidf_(acc2[i][j] + bgs[c]);
      out[(size_t)r * CC + c] = gate * acc1[i][j];
    }
  }
}

extern "C" void kernel_launch(void* const* d_in, const int* in_sizes, int n_in,
                              void* d_out, int out_size, void* d_ws, size_t ws_size,
                              hipStream_t stream) {
  const float* a_i  = (const float*)d_in[0];
  const float* s_i  = (const float*)d_in[1];
  const float* z_ij = (const float*)d_in[2];
  const float* beta = (const float*)d_in[3];
  const float* Wq   = (const float*)d_in[4];
  const float* bq   = (const float*)d_in[5];
  const float* Wk   = (const float*)d_in[6];
  const float* Wv   = (const float*)d_in[7];
  const float* Wg   = (const float*)d_in[8];
  const float* Wo   = (const float*)d_in[9];
  const float* ada_ln2_w = (const float*)d_in[10];
  const float* ada_Wl = (const float*)d_in[11];
  const float* ada_bl = (const float*)d_in[12];
  const float* ada_Wnb = (const float*)d_in[13];
  const float* lnz_w = (const float*)d_in[14];
  const float* lnz_b = (const float*)d_in[15];
  const float* Wz  = (const float*)d_in[16];
  const float* Wgs = (const float*)d_in[17];
  const float* bgs = (const float*)d_in[18];
  float* out = (float*)d_out;

  float* ws = (float*)d_ws;
  const size_t RC = (size_t)NB * NN * CC;   // 786432
  const size_t RS = (size_t)NB * NN * CS;   // 393216
  float* aln   = ws;
  float* sln   = aln + RC;
  float* acond = sln + RS;
  float* qb    = acond + RC;
  float* kb    = qb + RC;
  float* vb    = kb + RC;
  float* gb    = vb + RC;
  float* gob   = gb + RC;
  float* biasb = gob + RC;                  // B*H*N*N = 8388608 floats

  k_ln<<<NB * NN, 256, 0, stream>>>(a_i, s_i, ada_ln2_w, aln, sln);
  k_adaln<<<dim3(CC / 64, NB * NN / 64), 256, 0, stream>>>(
      sln, aln, ada_Wl, ada_bl, ada_Wnb, acond);
  k_pairbias<<<NB * NN * (NN / 32), 256, 0, stream>>>(
      z_ij, beta, lnz_w, lnz_b, Wz, biasb);
  k_qkvg<<<dim3(CC / 64, NB * NN / 64), 256, 0, stream>>>(
      acond, Wq, bq, Wk, Wv, Wg, qb, kb, vb, gb);
  k_attn<<<NB * NH * (NN / 32), 256, 0, stream>>>(qb, kb, vb, gb, biasb, gob);
  k_out<<<dim3(CC / 64, NB * NN / 64), 256, 0, stream>>>(
      gob, Wo, s_i, Wgs, bgs, out);
}

// Round 2
// 902.339 us; speedup vs baseline: 1.0224x; 1.0224x over previous
//
#include <hip/hip_runtime.h>
#include <hip/hip_bf16.h>

// Problem dims (hardcoded): B=2, N=512, C=768, H=16, D=48, CS=384, CZ=128
#define NB 2
#define NN 512
#define CC 768
#define NH 16
#define DD 48
#define CS 384
#define CZ 128

__device__ inline float2 wave_reduce_sum2(float s, float q) {
  #pragma unroll
  for (int off = 32; off > 0; off >>= 1) {
    s += __shfl_xor(s, off);
    q += __shfl_xor(q, off);
  }
  return make_float2(s, q);
}

__device__ inline float sigmoidf_(float x) { return 1.f / (1.f + __expf(-x)); }

// ---------------------------------------------------------------------------
// K1: LN(a_i) -> aln (no affine), LN(s_i)*w -> sln (weight only)
// grid = B*N = 1024 blocks, 256 threads
// ---------------------------------------------------------------------------
__global__ __launch_bounds__(256) void k_ln(
    const float* __restrict__ a_i, const float* __restrict__ s_i,
    const float* __restrict__ ln2w,
    float* __restrict__ aln, float* __restrict__ sln) {
  int r = blockIdx.x, t = threadIdx.x;
  int lane = t & 63, w = t >> 6;
  __shared__ float red[2][4];

  // ---- a row (768) ----
  const float* ar = a_i + (size_t)r * CC;
  float x0 = ar[t], x1 = ar[t + 256], x2 = ar[t + 512];
  float s = x0 + x1 + x2, sq = x0 * x0 + x1 * x1 + x2 * x2;
  float2 rs = wave_reduce_sum2(s, sq);
  if (lane == 0) { red[0][w] = rs.x; red[1][w] = rs.y; }
  __syncthreads();
  float S = red[0][0] + red[0][1] + red[0][2] + red[0][3];
  float SQ = red[1][0] + red[1][1] + red[1][2] + red[1][3];
  float mean = S * (1.f / CC);
  float var = SQ * (1.f / CC) - mean * mean;
  float rstd = rsqrtf(var + 1e-5f);
  float* alr = aln + (size_t)r * CC;
  alr[t] = (x0 - mean) * rstd;
  alr[t + 256] = (x1 - mean) * rstd;
  alr[t + 512] = (x2 - mean) * rstd;

  // ---- s row (384) ----
  const float* sr = s_i + (size_t)r * CS;
  float y0 = sr[t];
  float y1 = (t < 128) ? sr[256 + t] : 0.f;
  float s2 = y0 + y1, sq2 = y0 * y0 + y1 * y1;
  float2 rs2 = wave_reduce_sum2(s2, sq2);
  __syncthreads();  // protect red[] reads above
  if (lane == 0) { red[0][w] = rs2.x; red[1][w] = rs2.y; }
  __syncthreads();
  float S2 = red[0][0] + red[0][1] + red[0][2] + red[0][3];
  float SQ2 = red[1][0] + red[1][1] + red[1][2] + red[1][3];
  float mean2 = S2 * (1.f / CS);
  float var2 = SQ2 * (1.f / CS) - mean2 * mean2;
  float rstd2 = rsqrtf(var2 + 1e-5f);
  float* slr = sln + (size_t)r * CS;
  slr[t] = (y0 - mean2) * rstd2 * ln2w[t];
  if (t < 128) slr[256 + t] = (y1 - mean2) * rstd2 * ln2w[256 + t];
}

// ---------------------------------------------------------------------------
// K2: acond = sigmoid(sln@Wl^T + bl) * aln + sln@Wnb^T
// M=1024, N=768, K=384. grid (12,16), 256 thr, 64x64 tile, 4x4 micro.
// ---------------------------------------------------------------------------
__global__ __launch_bounds__(256) void k_adaln(
    const float* __restrict__ sln, const float* __restrict__ aln,
    const float* __restrict__ Wl, const float* __restrict__ bl,
    const float* __restrict__ Wnb, float* __restrict__ acond) {
  __shared__ float As[16][65], B1[16][65], B2[16][65];
  int cb = blockIdx.x * 64, rb = blockIdx.y * 64;
  int t = threadIdx.x, tr = t >> 4, tc = t & 15;
  int lk = t & 15, lr = t >> 4;
  float acc1[4][4] = {}, acc2[4][4] = {};
  for (int kb = 0; kb < CS; kb += 16) {
    #pragma unroll
    for (int i = 0; i < 4; ++i) {
      int row = lr + i * 16;
      As[lk][row] = sln[(size_t)(rb + row) * CS + kb + lk];
      B1[lk][row] = Wl[(size_t)(cb + row) * CS + kb + lk];
      B2[lk][row] = Wnb[(size_t)(cb + row) * CS + kb + lk];
    }
    __syncthreads();
    #pragma unroll
    for (int k = 0; k < 16; ++k) {
      float a[4], b1[4], b2[4];
      #pragma unroll
      for (int i = 0; i < 4; ++i) a[i] = As[k][tr * 4 + i];
      #pragma unroll
      for (int j = 0; j < 4; ++j) { b1[j] = B1[k][tc * 4 + j]; b2[j] = B2[k][tc * 4 + j]; }
      #pragma unroll
      for (int i = 0; i < 4; ++i)
        #pragma unroll
        for (int j = 0; j < 4; ++j) {
          acc1[i][j] += a[i] * b1[j];
          acc2[i][j] += a[i] * b2[j];
        }
    }
    __syncthreads();
  }
  #pragma unroll
  for (int i = 0; i < 4; ++i) {
    int r = rb + tr * 4 + i;
    #pragma unroll
    for (int j = 0; j < 4; ++j) {
      int c = cb + tc * 4 + j;
      float sig = sigmoidf_(acc1[i][j] + bl[c]);
      acond[(size_t)r * CC + c] = sig * aln[(size_t)r * CC + c] + acc2[i][j];
    }
  }
}

// ---------------------------------------------------------------------------
// K3: fused QKVG, one output matrix per blockIdx.z (occupancy: 192->768 blocks)
// q=(acond@Wq^T+bq)/sqrt(D), k, v, g=sigmoid(acond@Wg^T)
// M=1024, N=768, K=768. grid (12,16,4), 256 thr, 64x64 tile, 4x4 micro.
// ---------------------------------------------------------------------------
__global__ __launch_bounds__(256) void k_qkvg(
    const float* __restrict__ acond,
    const float* __restrict__ Wq, const float* __restrict__ bq,
    const float* __restrict__ Wk, const float* __restrict__ Wv,
    const float* __restrict__ Wg,
    float* __restrict__ qo, float* __restrict__ ko,
    float* __restrict__ vo, float* __restrict__ go) {
  __shared__ float As[16][68], Bs[16][68];
  int zid = blockIdx.z;
  const float* W = (zid == 0) ? Wq : (zid == 1) ? Wk : (zid == 2) ? Wv : Wg;
  int cb = blockIdx.x * 64, rb = blockIdx.y * 64;
  int t = threadIdx.x, tr = t >> 4, tc = t & 15;
  int lk = t & 15, lr = t >> 4;
  float acc[4][4] = {};
  for (int kb = 0; kb < CC; kb += 16) {
    #pragma unroll
    for (int i = 0; i < 4; ++i) {
      int row = lr + i * 16;
      As[lk][row] = acond[(size_t)(rb + row) * CC + kb + lk];
      Bs[lk][row] = W[(size_t)(cb + row) * CC + kb + lk];
    }
    __syncthreads();
    #pragma unroll
    for (int k = 0; k < 16; ++k) {
      float a[4], bb[4];
      #pragma unroll
      for (int i = 0; i < 4; ++i) a[i] = As[k][tr * 4 + i];
      #pragma unroll
      for (int j = 0; j < 4; ++j) bb[j] = Bs[k][tc * 4 + j];
      #pragma unroll
      for (int i = 0; i < 4; ++i)
        #pragma unroll
        for (int j = 0; j < 4; ++j) acc[i][j] += a[i] * bb[j];
    }
    __syncthreads();
  }
  const float qscale = 0.14433756729740643f;  // 1/sqrt(48)
  #pragma unroll
  for (int i = 0; i < 4; ++i) {
    int r = rb + tr * 4 + i;
    #pragma unroll
    for (int j = 0; j < 4; ++j) {
      int c = cb + tc * 4 + j;
      size_t o = (size_t)r * CC + c;
      if (zid == 0)      qo[o] = (acc[i][j] + bq[c]) * qscale;
      else if (zid == 1) ko[o] = acc[i][j];
      else if (zid == 2) vo[o] = acc[i][j];
      else               go[o] = sigmoidf_(acc[i][j]);
    }
  }
}

// ---------------------------------------------------------------------------
// K4a: precompute Wzp[h][c] = lnzw[c]*Wz[h][c];  TK[h]=sum_c Wzp[h][c];
//      TK[16+h] = sum_c lnzb[c]*Wz[h][c].  1 block, 256 thr.
// ---------------------------------------------------------------------------
__global__ __launch_bounds__(256) void k_wzprep(
    const float* __restrict__ lnzw, const float* __restrict__ lnzb,
    const float* __restrict__ Wz, float* __restrict__ Wzp,
    float* __restrict__ TK) {
  int t = threadIdx.x;
  for (int idx = t; idx < NH * CZ; idx += 256)
    Wzp[idx] = lnzw[idx & (CZ - 1)] * Wz[idx];
  if (t < 32) {
    int h = t & 15;
    const float* wr = Wz + (size_t)h * CZ;
    const float* coef = (t < 16) ? lnzw : lnzb;
    float acc = 0.f;
    for (int c = 0; c < CZ; ++c) acc += coef[c] * wr[c];
    TK[(t < 16) ? h : 16 + h] = acc;
  }
}

// ---------------------------------------------------------------------------
// K4b: pair bias, thread-per-row, fused LN via linearity:
//   out[h] = rstd*(S_h - mean*T_h) + Kb_h + beta
//   S_h = sum_c z_c * Wzp[h][c]   (Wzp wave-uniform -> s_load, SGPR operands)
// grid = B*N*(N/256) = 2048 blocks, 256 thr; thread t owns row j = jt*256+t.
// 16 independent accumulators -> full FMA ILP; zero LDS; zero shuffles.
// ---------------------------------------------------------------------------
__global__ __launch_bounds__(256) void k_pairbias(
    const float* __restrict__ z, const float* __restrict__ beta,
    const float* __restrict__ Wzp, const float* __restrict__ TK,
    float* __restrict__ bias) {
  int blk = blockIdx.x;
  int jt = blk & 1, i = (blk >> 1) & (NN - 1), b = blk >> 10;
  int j = jt * 256 + threadIdx.x;

  const float4* zr = (const float4*)(z + ((size_t)(b * NN + i) * NN + j) * CZ);
  float S[16];
  #pragma unroll
  for (int h = 0; h < 16; ++h) S[h] = 0.f;
  float sum = 0.f, sq = 0.f;
  for (int c4 = 0; c4 < CZ / 4; ++c4) {
    float4 zv = zr[c4];
    sum += (zv.x + zv.y) + (zv.z + zv.w);
    sq += zv.x * zv.x + zv.y * zv.y + zv.z * zv.z + zv.w * zv.w;
    const float* wp = Wzp + c4 * 4;
    #pragma unroll
    for (int h = 0; h < 16; ++h) {
      S[h] += zv.x * wp[h * CZ + 0] + zv.y * wp[h * CZ + 1] +
              zv.z * wp[h * CZ + 2] + zv.w * wp[h * CZ + 3];
    }
  }
  float mean = sum * (1.f / CZ);
  float var = sq * (1.f / CZ) - mean * mean;
  float rstd = rsqrtf(var + 1e-5f);
  float bet = beta[((size_t)(b * NN + i)) * NN + j];
  size_t obase = (((size_t)b * NH) * NN + i) * NN + j;
  #pragma unroll
  for (int h = 0; h < 16; ++h) {
    bias[obase + (size_t)h * NN * NN] =
        rstd * (S[h] - mean * TK[h]) + TK[16 + h] + bet;
  }
}

// ---------------------------------------------------------------------------
// K5: flash attention + g-gating. block per (b,h,32-row q tile). 256 thr.
// Wave-parallel online softmax: 8 lanes per score row.
// ---------------------------------------------------------------------------
__global__ __launch_bounds__(256) void k_attn(
    const float* __restrict__ q, const float* __restrict__ k,
    const float* __restrict__ v, const float* __restrict__ g,
    const float* __restrict__ bias, float* __restrict__ go_out) {
  __shared__ __align__(16) float qs[32][49];
  __shared__ __align__(16) float ks[64][49];
  __shared__ __align__(16) float vs[64][49];
  __shared__ __align__(16) float ps[32][65];
  __shared__ __align__(16) float bs[32][65];
  __shared__ float mrow[32], lrow[32], crow[32];
  int blk = blockIdx.x;
  int it = blk & 15, h = (blk >> 4) & 15, b = blk >> 8;
  int ibase = it * 32;
  int t = threadIdx.x;
  int tr = t >> 4, tc = t & 15;  // scores: qi=tr*2+i, ji=tc*4+j
  int td = t & 15;               // pv: qi=tr*2+i, d=td*3+dd
  int sr = t >> 3, sl = t & 7;   // softmax: row sr, 8 lanes per row

  for (int idx = t; idx < 32 * 48; idx += 256) {
    int r = idx / 48, c = idx % 48;
    qs[r][c] = q[((size_t)(b * NN) + ibase + r) * CC + h * DD + c];
  }
  if (t < 32) { mrow[t] = -1e30f; lrow[t] = 0.f; }
  float acc[2][3] = {};
  const size_t bh = (size_t)b * NH + h;

  for (int jb = 0; jb < NN; jb += 64) {
    __syncthreads();
    for (int idx = t; idx < 64 * 48; idx += 256) {
      int r = idx / 48, c = idx % 48;
      size_t src = ((size_t)(b * NN) + jb + r) * CC + h * DD + c;
      ks[r][c] = k[src];
      vs[r][c] = v[src];
    }
    for (int idx = t; idx < 32 * 64; idx += 256) {
      int r = idx >> 6, c = idx & 63;
      bs[r][c] = bias[(bh * NN + ibase + r) * NN + jb + c];
    }
    __syncthreads();
    // scores
    float sc[2][4] = {};
    #pragma unroll
    for (int d = 0; d < DD; ++d) {
      float a0 = qs[tr * 2][d], a1 = qs[tr * 2 + 1][d];
      #pragma unroll
      for (int j = 0; j < 4; ++j) {
        float bk = ks[tc * 4 + j][d];
        sc[0][j] += a0 * bk;
        sc[1][j] += a1 * bk;
      }
    }
    #pragma unroll
    for (int i = 0; i < 2; ++i)
      #pragma unroll
      for (int j = 0; j < 4; ++j)
        ps[tr * 2 + i][tc * 4 + j] = sc[i][j] + bs[tr * 2 + i][tc * 4 + j];
    __syncthreads();
    // wave-parallel online softmax: 8 lanes per row, shfl_xor over 1,2,4
    {
      float lm = -1e30f;
      #pragma unroll
      for (int jj = 0; jj < 8; ++jj) lm = fmaxf(lm, ps[sr][sl * 8 + jj]);
      lm = fmaxf(lm, __shfl_xor(lm, 1));
      lm = fmaxf(lm, __shfl_xor(lm, 2));
      lm = fmaxf(lm, __shfl_xor(lm, 4));
      float m_old = mrow[sr];
      float rmax = fmaxf(m_old, lm);
      float lsum = 0.f;
      #pragma unroll
      for (int jj = 0; jj < 8; ++jj) {
        float p = __expf(ps[sr][sl * 8 + jj] - rmax);
        ps[sr][sl * 8 + jj] = p;
        lsum += p;
      }
      lsum += __shfl_xor(lsum, 1);
      lsum += __shfl_xor(lsum, 2);
      lsum += __shfl_xor(lsum, 4);
      if (sl == 0) {
        float corr = __expf(m_old - rmax);
        lrow[sr] = lrow[sr] * corr + lsum;
        mrow[sr] = rmax;
        crow[sr] = corr;
      }
    }
    __syncthreads();
    // PV
    float c0 = crow[tr * 2], c1 = crow[tr * 2 + 1];
    #pragma unroll
    for (int dd = 0; dd < 3; ++dd) { acc[0][dd] *= c0; acc[1][dd] *= c1; }
    #pragma unroll
    for (int ji = 0; ji < 64; ++ji) {
      float p0 = ps[tr * 2][ji], p1 = ps[tr * 2 + 1][ji];
      #pragma unroll
      for (int dd = 0; dd < 3; ++dd) {
        float vv = vs[ji][td * 3 + dd];
        acc[0][dd] += p0 * vv;
        acc[1][dd] += p1 * vv;
      }
    }
  }
  __syncthreads();
  #pragma unroll
  for (int i = 0; i < 2; ++i) {
    int qi = tr * 2 + i;
    float inv = 1.f / lrow[qi];
    #pragma unroll
    for (int dd = 0; dd < 3; ++dd) {
      int d = td * 3 + dd;
      size_t o = ((size_t)(b * NN) + ibase + qi) * CC + h * DD + d;
      go_out[o] = acc[i][dd] * inv * g[o];
    }
  }
}

// ---------------------------------------------------------------------------
// K6: out = sigmoid(s_i@Wgs^T + bgs) * (go@Wo^T)
// grid (12,16), 256 thr.
// ---------------------------------------------------------------------------
__global__ __launch_bounds__(256) void k_out(
    const float* __restrict__ go, const float* __restrict__ Wo,
    const float* __restrict__ s_i, const float* __restrict__ Wgs,
    const float* __restrict__ bgs, float* __restrict__ out) {
  __shared__ float As[16][65], Bs[16][65];
  int cb = blockIdx.x * 64, rb = blockIdx.y * 64;
  int t = threadIdx.x, tr = t >> 4, tc = t & 15;
  int lk = t & 15, lr = t >> 4;
  float acc1[4][4] = {}, acc2[4][4] = {};
  for (int kb = 0; kb < CC; kb += 16) {
    #pragma unroll
    for (int i = 0; i < 4; ++i) {
      int row = lr + i * 16;
      As[lk][row] = go[(size_t)(rb + row) * CC + kb + lk];
      Bs[lk][row] = Wo[(size_t)(cb + row) * CC + kb + lk];
    }
    __syncthreads();
    #pragma unroll
    for (int k = 0; k < 16; ++k) {
      float a[4], bb[4];
      #pragma unroll
      for (int i = 0; i < 4; ++i) a[i] = As[k][tr * 4 + i];
      #pragma unroll
      for (int j = 0; j < 4; ++j) bb[j] = Bs[k][tc * 4 + j];
      #pragma unroll
      for (int i = 0; i < 4; ++i)
        #pragma unroll
        for (int j = 0; j < 4; ++j) acc1[i][j] += a[i] * bb[j];
    }
    __syncthreads();
  }
  for (int kb = 0; kb < CS; kb += 16) {
    #pragma unroll
    for (int i = 0; i < 4; ++i) {
      int row = lr + i * 16;
      As[lk][row] = s_i[(size_t)(rb + row) * CS + kb + lk];
      Bs[lk][row] = Wgs[(size_t)(cb + row) * CS + kb + lk];
    }
    __syncthreads();
    #pragma unroll
    for (int k = 0; k < 16; ++k) {
      float a[4], bb[4];
      #pragma unroll
      for (int i = 0; i < 4; ++i) a[i] = As[k][tr * 4 + i];
      #pragma unroll
      for (int j = 0; j < 4; ++j) bb[j] = Bs[k][tc * 4 + j];
      #pragma unroll
      for (int i = 0; i < 4; ++i)
        #pragma unroll
        for (int j = 0; j < 4; ++j) acc2[i][j] += a[i] * bb[j];
    }
    __syncthreads();
  }
  #pragma unroll
  for (int i = 0; i < 4; ++i) {
    int r = rb + tr * 4 + i;
    #pragma unroll
    for (int j = 0; j < 4; ++j) {
      int c = cb + tc * 4 + j;
      float gate = sigmoidf_(acc2[i][j] + bgs[c]);
      out[(size_t)r * CC + c] = gate * acc1[i][j];
    }
  }
}

extern "C" void kernel_launch(void* const* d_in, const int* in_sizes, int n_in,
                              void* d_out, int out_size, void* d_ws, size_t ws_size,
                              hipStream_t stream) {
  const float* a_i  = (const float*)d_in[0];
  const float* s_i  = (const float*)d_in[1];
  const float* z_ij = (const float*)d_in[2];
  const float* beta = (const float*)d_in[3];
  const float* Wq   = (const float*)d_in[4];
  const float* bq   = (const float*)d_in[5];
  const float* Wk   = (const float*)d_in[6];
  const float* Wv   = (const float*)d_in[7];
  const float* Wg   = (const float*)d_in[8];
  const float* Wo   = (const float*)d_in[9];
  const float* ada_ln2_w = (const float*)d_in[10];
  const float* ada_Wl = (const float*)d_in[11];
  const float* ada_bl = (const float*)d_in[12];
  const float* ada_Wnb = (const float*)d_in[13];
  const float* lnz_w = (const float*)d_in[14];
  const float* lnz_b = (const float*)d_in[15];
  const float* Wz  = (const float*)d_in[16];
  const float* Wgs = (const float*)d_in[17];
  const float* bgs = (const float*)d_in[18];
  float* out = (float*)d_out;

  float* ws = (float*)d_ws;
  const size_t RC = (size_t)NB * NN * CC;   // 786432
  const size_t RS = (size_t)NB * NN * CS;   // 393216
  float* aln   = ws;
  float* sln   = aln + RC;
  float* acond = sln + RS;
  float* qb    = acond + RC;
  float* kb    = qb + RC;
  float* vb    = kb + RC;
  float* gb    = vb + RC;
  float* gob   = gb + RC;
  float* biasb = gob + RC;                  // B*H*N*N = 8388608 floats
  float* Wzp   = biasb + (size_t)NB * NH * NN * NN;  // 2048
  float* TK    = Wzp + NH * CZ;                      // 32

  k_ln<<<NB * NN, 256, 0, stream>>>(a_i, s_i, ada_ln2_w, aln, sln);
  k_wzprep<<<1, 256, 0, stream>>>(lnz_w, lnz_b, Wz, Wzp, TK);
  k_adaln<<<dim3(CC / 64, NB * NN / 64), 256, 0, stream>>>(
      sln, aln, ada_Wl, ada_bl, ada_Wnb, acond);
  k_pairbias<<<NB * NN * (NN / 256), 256, 0, stream>>>(
      z_ij, beta, Wzp, TK, biasb);
  k_qkvg<<<dim3(CC / 64, NB * NN / 64, 4), 256, 0, stream>>>(
      acond, Wq, bq, Wk, Wv, Wg, qb, kb, vb, gb);
  k_attn<<<NB * NH * (NN / 32), 256, 0, stream>>>(qb, kb, vb, gb, biasb, gob);
  k_out<<<dim3(CC / 64, NB * NN / 64), 256, 0, stream>>>(
      gob, Wo, s_i, Wgs, bgs, out);
}

// Round 3
// 813.136 us; speedup vs baseline: 1.1346x; 1.1097x over previous
//
#include <hip/hip_runtime.h>
#include <hip/hip_bf16.h>

// Problem dims (hardcoded): B=2, N=512, C=768, H=16, D=48, CS=384, CZ=128
#define NB 2
#define NN 512
#define CC 768
#define NH 16
#define DD 48
#define CS 384
#define CZ 128

__device__ inline float2 wave_reduce_sum2(float s, float q) {
  #pragma unroll
  for (int off = 32; off > 0; off >>= 1) {
    s += __shfl_xor(s, off);
    q += __shfl_xor(q, off);
  }
  return make_float2(s, q);
}

__device__ inline float sigmoidf_(float x) { return 1.f / (1.f + __expf(-x)); }

// ---------------------------------------------------------------------------
// K1: LN(a_i) -> aln (no affine), LN(s_i)*w -> sln (weight only)
// grid = B*N = 1024 blocks, 256 threads
// ---------------------------------------------------------------------------
__global__ __launch_bounds__(256) void k_ln(
    const float* __restrict__ a_i, const float* __restrict__ s_i,
    const float* __restrict__ ln2w,
    float* __restrict__ aln, float* __restrict__ sln) {
  int r = blockIdx.x, t = threadIdx.x;
  int lane = t & 63, w = t >> 6;
  __shared__ float red[2][4];

  // ---- a row (768) ----
  const float* ar = a_i + (size_t)r * CC;
  float x0 = ar[t], x1 = ar[t + 256], x2 = ar[t + 512];
  float s = x0 + x1 + x2, sq = x0 * x0 + x1 * x1 + x2 * x2;
  float2 rs = wave_reduce_sum2(s, sq);
  if (lane == 0) { red[0][w] = rs.x; red[1][w] = rs.y; }
  __syncthreads();
  float S = red[0][0] + red[0][1] + red[0][2] + red[0][3];
  float SQ = red[1][0] + red[1][1] + red[1][2] + red[1][3];
  float mean = S * (1.f / CC);
  float var = SQ * (1.f / CC) - mean * mean;
  float rstd = rsqrtf(var + 1e-5f);
  float* alr = aln + (size_t)r * CC;
  alr[t] = (x0 - mean) * rstd;
  alr[t + 256] = (x1 - mean) * rstd;
  alr[t + 512] = (x2 - mean) * rstd;

  // ---- s row (384) ----
  const float* sr = s_i + (size_t)r * CS;
  float y0 = sr[t];
  float y1 = (t < 128) ? sr[256 + t] : 0.f;
  float s2 = y0 + y1, sq2 = y0 * y0 + y1 * y1;
  float2 rs2 = wave_reduce_sum2(s2, sq2);
  __syncthreads();  // protect red[] reads above
  if (lane == 0) { red[0][w] = rs2.x; red[1][w] = rs2.y; }
  __syncthreads();
  float S2 = red[0][0] + red[0][1] + red[0][2] + red[0][3];
  float SQ2 = red[1][0] + red[1][1] + red[1][2] + red[1][3];
  float mean2 = S2 * (1.f / CS);
  float var2 = SQ2 * (1.f / CS) - mean2 * mean2;
  float rstd2 = rsqrtf(var2 + 1e-5f);
  float* slr = sln + (size_t)r * CS;
  slr[t] = (y0 - mean2) * rstd2 * ln2w[t];
  if (t < 128) slr[256 + t] = (y1 - mean2) * rstd2 * ln2w[256 + t];
}

// ---------------------------------------------------------------------------
// K2: acond = sigmoid(sln@Wl^T + bl) * aln + sln@Wnb^T
// M=1024, N=768, K=384. grid (12,16), 256 thr, 64x64 tile, 4x4 micro.
// LDS fragments read as float4 (ds_read_b128); tiles padded to 68 for 16B
// alignment (bank math: A-frag 16-way broadcast / 16 banks, B-frag 2-way=free)
// ---------------------------------------------------------------------------
__global__ __launch_bounds__(256) void k_adaln(
    const float* __restrict__ sln, const float* __restrict__ aln,
    const float* __restrict__ Wl, const float* __restrict__ bl,
    const float* __restrict__ Wnb, float* __restrict__ acond) {
  __shared__ __align__(16) float As[16][68], B1[16][68], B2[16][68];
  int cb = blockIdx.x * 64, rb = blockIdx.y * 64;
  int t = threadIdx.x, tr = t >> 4, tc = t & 15;
  int lk = t & 15, lr = t >> 4;
  float acc1[4][4] = {}, acc2[4][4] = {};
  for (int kb = 0; kb < CS; kb += 16) {
    #pragma unroll
    for (int i = 0; i < 4; ++i) {
      int row = lr + i * 16;
      As[lk][row] = sln[(size_t)(rb + row) * CS + kb + lk];
      B1[lk][row] = Wl[(size_t)(cb + row) * CS + kb + lk];
      B2[lk][row] = Wnb[(size_t)(cb + row) * CS + kb + lk];
    }
    __syncthreads();
    #pragma unroll
    for (int k = 0; k < 16; ++k) {
      float4 av = ((const float4*)&As[k][0])[tr];
      float4 b1v = ((const float4*)&B1[k][0])[tc];
      float4 b2v = ((const float4*)&B2[k][0])[tc];
      float a[4] = {av.x, av.y, av.z, av.w};
      float b1a[4] = {b1v.x, b1v.y, b1v.z, b1v.w};
      float b2a[4] = {b2v.x, b2v.y, b2v.z, b2v.w};
      #pragma unroll
      for (int i = 0; i < 4; ++i)
        #pragma unroll
        for (int j = 0; j < 4; ++j) {
          acc1[i][j] += a[i] * b1a[j];
          acc2[i][j] += a[i] * b2a[j];
        }
    }
    __syncthreads();
  }
  #pragma unroll
  for (int i = 0; i < 4; ++i) {
    int r = rb + tr * 4 + i;
    #pragma unroll
    for (int j = 0; j < 4; ++j) {
      int c = cb + tc * 4 + j;
      float sig = sigmoidf_(acc1[i][j] + bl[c]);
      acond[(size_t)r * CC + c] = sig * aln[(size_t)r * CC + c] + acc2[i][j];
    }
  }
}

// ---------------------------------------------------------------------------
// K3: fused QKVG, one output matrix per blockIdx.z.
// q=(acond@Wq^T+bq)/sqrt(D), k, v, g=sigmoid(acond@Wg^T)
// M=1024, N=768, K=768. grid (12,16,4), 256 thr, 64x64 tile, float4 LDS reads.
// ---------------------------------------------------------------------------
__global__ __launch_bounds__(256) void k_qkvg(
    const float* __restrict__ acond,
    const float* __restrict__ Wq, const float* __restrict__ bq,
    const float* __restrict__ Wk, const float* __restrict__ Wv,
    const float* __restrict__ Wg,
    float* __restrict__ qo, float* __restrict__ ko,
    float* __restrict__ vo, float* __restrict__ go) {
  __shared__ __align__(16) float As[16][68], Bs[16][68];
  int zid = blockIdx.z;
  const float* W = (zid == 0) ? Wq : (zid == 1) ? Wk : (zid == 2) ? Wv : Wg;
  int cb = blockIdx.x * 64, rb = blockIdx.y * 64;
  int t = threadIdx.x, tr = t >> 4, tc = t & 15;
  int lk = t & 15, lr = t >> 4;
  float acc[4][4] = {};
  for (int kb = 0; kb < CC; kb += 16) {
    #pragma unroll
    for (int i = 0; i < 4; ++i) {
      int row = lr + i * 16;
      As[lk][row] = acond[(size_t)(rb + row) * CC + kb + lk];
      Bs[lk][row] = W[(size_t)(cb + row) * CC + kb + lk];
    }
    __syncthreads();
    #pragma unroll
    for (int k = 0; k < 16; ++k) {
      float4 av = ((const float4*)&As[k][0])[tr];
      float4 bv = ((const float4*)&Bs[k][0])[tc];
      float a[4] = {av.x, av.y, av.z, av.w};
      float bb[4] = {bv.x, bv.y, bv.z, bv.w};
      #pragma unroll
      for (int i = 0; i < 4; ++i)
        #pragma unroll
        for (int j = 0; j < 4; ++j) acc[i][j] += a[i] * bb[j];
    }
    __syncthreads();
  }
  const float qscale = 0.14433756729740643f;  // 1/sqrt(48)
  #pragma unroll
  for (int i = 0; i < 4; ++i) {
    int r = rb + tr * 4 + i;
    #pragma unroll
    for (int j = 0; j < 4; ++j) {
      int c = cb + tc * 4 + j;
      size_t o = (size_t)r * CC + c;
      if (zid == 0)      qo[o] = (acc[i][j] + bq[c]) * qscale;
      else if (zid == 1) ko[o] = acc[i][j];
      else if (zid == 2) vo[o] = acc[i][j];
      else               go[o] = sigmoidf_(acc[i][j]);
    }
  }
}

// ---------------------------------------------------------------------------
// K4a: precompute Wzp[h][c] = lnzw[c]*Wz[h][c];  TK[h]=sum_c Wzp[h][c];
//      TK[16+h] = sum_c lnzb[c]*Wz[h][c].  1 block, 256 thr.
// ---------------------------------------------------------------------------
__global__ __launch_bounds__(256) void k_wzprep(
    const float* __restrict__ lnzw, const float* __restrict__ lnzb,
    const float* __restrict__ Wz, float* __restrict__ Wzp,
    float* __restrict__ TK) {
  int t = threadIdx.x;
  for (int idx = t; idx < NH * CZ; idx += 256)
    Wzp[idx] = lnzw[idx & (CZ - 1)] * Wz[idx];
  if (t < 32) {
    int h = t & 15;
    const float* wr = Wz + (size_t)h * CZ;
    const float* coef = (t < 16) ? lnzw : lnzb;
    float acc = 0.f;
    for (int c = 0; c < CZ; ++c) acc += coef[c] * wr[c];
    TK[(t < 16) ? h : 16 + h] = acc;
  }
}

// ---------------------------------------------------------------------------
// K4b: pair bias via LN-linearity: out[h] = rstd*(S_h - mean*T_h) + Kb_h + beta
// Coalescing-first layout: 4 lanes per row (lane q reads float4 col4=it*4+q ->
// each instr reads 16 fully-used 64B chunks), 2 rows per lane (amortize Wzp
// L1 re-reads), butterfly shfl_xor(1,2) reduce within the 4-lane group.
// grid = B*N*(N/128) = 4096 blocks, 256 thr; block covers 128 j (wave: 32 j).
// ---------------------------------------------------------------------------
__global__ __launch_bounds__(256) void k_pairbias(
    const float* __restrict__ z, const float* __restrict__ beta,
    const float* __restrict__ Wzp, const float* __restrict__ TK,
    float* __restrict__ bias) {
  int blk = blockIdx.x;
  int jb = blk & 3, i = (blk >> 2) & (NN - 1), b = blk >> 11;
  int t = threadIdx.x, w = t >> 6, lane = t & 63;
  int g = lane >> 2, q = lane & 3;
  int jA = jb * 128 + w * 32 + g;   // rows this lane-group owns
  int jB = jA + 16;

  const float4* zA = (const float4*)(z + ((size_t)(b * NN + i) * NN + jA) * CZ);
  const float4* zB = (const float4*)(z + ((size_t)(b * NN + i) * NN + jB) * CZ);
  const float4* Wzp4 = (const float4*)Wzp;

  float SA[16], SB[16];
  #pragma unroll
  for (int h = 0; h < 16; ++h) { SA[h] = 0.f; SB[h] = 0.f; }
  float sumA = 0.f, sqA = 0.f, sumB = 0.f, sqB = 0.f;

  #pragma unroll
  for (int it = 0; it < 8; ++it) {
    int col4 = it * 4 + q;
    float4 a = zA[col4];
    float4 c = zB[col4];
    sumA += (a.x + a.y) + (a.z + a.w);
    sqA += a.x * a.x + a.y * a.y + a.z * a.z + a.w * a.w;
    sumB += (c.x + c.y) + (c.z + c.w);
    sqB += c.x * c.x + c.y * c.y + c.z * c.z + c.w * c.w;
    #pragma unroll
    for (int h = 0; h < 16; ++h) {
      float4 wv = Wzp4[h * 32 + col4];
      SA[h] += a.x * wv.x + a.y * wv.y + a.z * wv.z + a.w * wv.w;
      SB[h] += c.x * wv.x + c.y * wv.y + c.z * wv.z + c.w * wv.w;
    }
  }
  // butterfly reduce across the 4-lane group (all lanes end with full sums)
  #pragma unroll
  for (int h = 0; h < 16; ++h) {
    SA[h] += __shfl_xor(SA[h], 1); SA[h] += __shfl_xor(SA[h], 2);
    SB[h] += __shfl_xor(SB[h], 1); SB[h] += __shfl_xor(SB[h], 2);
  }
  sumA += __shfl_xor(sumA, 1); sumA += __shfl_xor(sumA, 2);
  sqA  += __shfl_xor(sqA, 1);  sqA  += __shfl_xor(sqA, 2);
  sumB += __shfl_xor(sumB, 1); sumB += __shfl_xor(sumB, 2);
  sqB  += __shfl_xor(sqB, 1);  sqB  += __shfl_xor(sqB, 2);

  float meanA = sumA * (1.f / CZ);
  float varA = fmaxf(sqA * (1.f / CZ) - meanA * meanA, 0.f);
  float rstdA = rsqrtf(varA + 1e-5f);
  float meanB = sumB * (1.f / CZ);
  float varB = fmaxf(sqB * (1.f / CZ) - meanB * meanB, 0.f);
  float rstdB = rsqrtf(varB + 1e-5f);
  float betA = beta[((size_t)(b * NN + i)) * NN + jA];
  float betB = beta[((size_t)(b * NN + i)) * NN + jB];
  size_t obase = (((size_t)b * NH) * NN + i) * NN;
  // lane q writes planes h = q*4+m: per instr 4 h-planes x 16 consecutive j
  #pragma unroll
  for (int m = 0; m < 4; ++m) {
    int h = q * 4 + m;
    size_t po = obase + (size_t)h * NN * NN;
    bias[po + jA] = rstdA * (SA[h] - meanA * TK[h]) + TK[16 + h] + betA;
    bias[po + jB] = rstdB * (SB[h] - meanB * TK[h]) + TK[16 + h] + betB;
  }
}

// ---------------------------------------------------------------------------
// K5: flash attention + g-gating. block per (b,h,32-row q tile). 256 thr.
// Wave-parallel online softmax: 8 lanes per score row.
// ---------------------------------------------------------------------------
__global__ __launch_bounds__(256) void k_attn(
    const float* __restrict__ q, const float* __restrict__ k,
    const float* __restrict__ v, const float* __restrict__ g,
    const float* __restrict__ bias, float* __restrict__ go_out) {
  __shared__ __align__(16) float qs[32][49];
  __shared__ __align__(16) float ks[64][49];
  __shared__ __align__(16) float vs[64][49];
  __shared__ __align__(16) float ps[32][65];
  __shared__ __align__(16) float bs[32][65];
  __shared__ float mrow[32], lrow[32], crow[32];
  int blk = blockIdx.x;
  int it = blk & 15, h = (blk >> 4) & 15, b = blk >> 8;
  int ibase = it * 32;
  int t = threadIdx.x;
  int tr = t >> 4, tc = t & 15;  // scores: qi=tr*2+i, ji=tc*4+j
  int td = t & 15;               // pv: qi=tr*2+i, d=td*3+dd
  int sr = t >> 3, sl = t & 7;   // softmax: row sr, 8 lanes per row

  for (int idx = t; idx < 32 * 48; idx += 256) {
    int r = idx / 48, c = idx % 48;
    qs[r][c] = q[((size_t)(b * NN) + ibase + r) * CC + h * DD + c];
  }
  if (t < 32) { mrow[t] = -1e30f; lrow[t] = 0.f; }
  float acc[2][3] = {};
  const size_t bh = (size_t)b * NH + h;

  for (int jb = 0; jb < NN; jb += 64) {
    __syncthreads();
    for (int idx = t; idx < 64 * 48; idx += 256) {
      int r = idx / 48, c = idx % 48;
      size_t src = ((size_t)(b * NN) + jb + r) * CC + h * DD + c;
      ks[r][c] = k[src];
      vs[r][c] = v[src];
    }
    for (int idx = t; idx < 32 * 64; idx += 256) {
      int r = idx >> 6, c = idx & 63;
      bs[r][c] = bias[(bh * NN + ibase + r) * NN + jb + c];
    }
    __syncthreads();
    // scores
    float sc[2][4] = {};
    #pragma unroll
    for (int d = 0; d < DD; ++d) {
      float a0 = qs[tr * 2][d], a1 = qs[tr * 2 + 1][d];
      #pragma unroll
      for (int j = 0; j < 4; ++j) {
        float bk = ks[tc * 4 + j][d];
        sc[0][j] += a0 * bk;
        sc[1][j] += a1 * bk;
      }
    }
    #pragma unroll
    for (int i = 0; i < 2; ++i)
      #pragma unroll
      for (int j = 0; j < 4; ++j)
        ps[tr * 2 + i][tc * 4 + j] = sc[i][j] + bs[tr * 2 + i][tc * 4 + j];
    __syncthreads();
    // wave-parallel online softmax: 8 lanes per row, shfl_xor over 1,2,4
    {
      float lm = -1e30f;
      #pragma unroll
      for (int jj = 0; jj < 8; ++jj) lm = fmaxf(lm, ps[sr][sl * 8 + jj]);
      lm = fmaxf(lm, __shfl_xor(lm, 1));
      lm = fmaxf(lm, __shfl_xor(lm, 2));
      lm = fmaxf(lm, __shfl_xor(lm, 4));
      float m_old = mrow[sr];
      float rmax = fmaxf(m_old, lm);
      float lsum = 0.f;
      #pragma unroll
      for (int jj = 0; jj < 8; ++jj) {
        float p = __expf(ps[sr][sl * 8 + jj] - rmax);
        ps[sr][sl * 8 + jj] = p;
        lsum += p;
      }
      lsum += __shfl_xor(lsum, 1);
      lsum += __shfl_xor(lsum, 2);
      lsum += __shfl_xor(lsum, 4);
      if (sl == 0) {
        float corr = __expf(m_old - rmax);
        lrow[sr] = lrow[sr] * corr + lsum;
        mrow[sr] = rmax;
        crow[sr] = corr;
      }
    }
    __syncthreads();
    // PV
    float c0 = crow[tr * 2], c1 = crow[tr * 2 + 1];
    #pragma unroll
    for (int dd = 0; dd < 3; ++dd) { acc[0][dd] *= c0; acc[1][dd] *= c1; }
    #pragma unroll
    for (int ji = 0; ji < 64; ++ji) {
      float p0 = ps[tr * 2][ji], p1 = ps[tr * 2 + 1][ji];
      #pragma unroll
      for (int dd = 0; dd < 3; ++dd) {
        float vv = vs[ji][td * 3 + dd];
        acc[0][dd] += p0 * vv;
        acc[1][dd] += p1 * vv;
      }
    }
  }
  __syncthreads();
  #pragma unroll
  for (int i = 0; i < 2; ++i) {
    int qi = tr * 2 + i;
    float inv = 1.f / lrow[qi];
    #pragma unroll
    for (int dd = 0; dd < 3; ++dd) {
      int d = td * 3 + dd;
      size_t o = ((size_t)(b * NN) + ibase + qi) * CC + h * DD + d;
      go_out[o] = acc[i][dd] * inv * g[o];
    }
  }
}

// ---------------------------------------------------------------------------
// K6: out = sigmoid(s_i@Wgs^T + bgs) * (go@Wo^T)
// grid (12,16), 256 thr, float4 LDS reads.
// ---------------------------------------------------------------------------
__global__ __launch_bounds__(256) void k_out(
    const float* __restrict__ go, const float* __restrict__ Wo,
    const float* __restrict__ s_i, const float* __restrict__ Wgs,
    const float* __restrict__ bgs, float* __restrict__ out) {
  __shared__ __align__(16) float As[16][68], Bs[16][68];
  int cb = blockIdx.x * 64, rb = blockIdx.y * 64;
  int t = threadIdx.x, tr = t >> 4, tc = t & 15;
  int lk = t & 15, lr = t >> 4;
  float acc1[4][4] = {}, acc2[4][4] = {};
  for (int kb = 0; kb < CC; kb += 16) {
    #pragma unroll
    for (int i = 0; i < 4; ++i) {
      int row = lr + i * 16;
      As[lk][row] = go[(size_t)(rb + row) * CC + kb + lk];
      Bs[lk][row] = Wo[(size_t)(cb + row) * CC + kb + lk];
    }
    __syncthreads();
    #pragma unroll
    for (int k = 0; k < 16; ++k) {
      float4 av = ((const float4*)&As[k][0])[tr];
      float4 bv = ((const float4*)&Bs[k][0])[tc];
      float a[4] = {av.x, av.y, av.z, av.w};
      float bb[4] = {bv.x, bv.y, bv.z, bv.w};
      #pragma unroll
      for (int i = 0; i < 4; ++i)
        #pragma unroll
        for (int j = 0; j < 4; ++j) acc1[i][j] += a[i] * bb[j];
    }
    __syncthreads();
  }
  for (int kb = 0; kb < CS; kb += 16) {
    #pragma unroll
    for (int i = 0; i < 4; ++i) {
      int row = lr + i * 16;
      As[lk][row] = s_i[(size_t)(rb + row) * CS + kb + lk];
      Bs[lk][row] = Wgs[(size_t)(cb + row) * CS + kb + lk];
    }
    __syncthreads();
    #pragma unroll
    for (int k = 0; k < 16; ++k) {
      float4 av = ((const float4*)&As[k][0])[tr];
      float4 bv = ((const float4*)&Bs[k][0])[tc];
      float a[4] = {av.x, av.y, av.z, av.w};
      float bb[4] = {bv.x, bv.y, bv.z, bv.w};
      #pragma unroll
      for (int i = 0; i < 4; ++i)
        #pragma unroll
        for (int j = 0; j < 4; ++j) acc2[i][j] += a[i] * bb[j];
    }
    __syncthreads();
  }
  #pragma unroll
  for (int i = 0; i < 4; ++i) {
    int r = rb + tr * 4 + i;
    #pragma unroll
    for (int j = 0; j < 4; ++j) {
      int c = cb + tc * 4 + j;
      float gate = sigmoidf_(acc2[i][j] + bgs[c]);
      out[(size_t)r * CC + c] = gate * acc1[i][j];
    }
  }
}

extern "C" void kernel_launch(void* const* d_in, const int* in_sizes, int n_in,
                              void* d_out, int out_size, void* d_ws, size_t ws_size,
                              hipStream_t stream) {
  const float* a_i  = (const float*)d_in[0];
  const float* s_i  = (const float*)d_in[1];
  const float* z_ij = (const float*)d_in[2];
  const float* beta = (const float*)d_in[3];
  const float* Wq   = (const float*)d_in[4];
  const float* bq   = (const float*)d_in[5];
  const float* Wk   = (const float*)d_in[6];
  const float* Wv   = (const float*)d_in[7];
  const float* Wg   = (const float*)d_in[8];
  const float* Wo   = (const float*)d_in[9];
  const float* ada_ln2_w = (const float*)d_in[10];
  const float* ada_Wl = (const float*)d_in[11];
  const float* ada_bl = (const float*)d_in[12];
  const float* ada_Wnb = (const float*)d_in[13];
  const float* lnz_w = (const float*)d_in[14];
  const float* lnz_b = (const float*)d_in[15];
  const float* Wz  = (const float*)d_in[16];
  const float* Wgs = (const float*)d_in[17];
  const float* bgs = (const float*)d_in[18];
  float* out = (float*)d_out;

  float* ws = (float*)d_ws;
  const size_t RC = (size_t)NB * NN * CC;   // 786432
  const size_t RS = (size_t)NB * NN * CS;   // 393216
  float* aln   = ws;
  float* sln   = aln + RC;
  float* acond = sln + RS;
  float* qb    = acond + RC;
  float* kb    = qb + RC;
  float* vb    = kb + RC;
  float* gb    = vb + RC;
  float* gob   = gb + RC;
  float* biasb = gob + RC;                  // B*H*N*N = 8388608 floats
  float* Wzp   = biasb + (size_t)NB * NH * NN * NN;  // 2048
  float* TK    = Wzp + NH * CZ;                      // 32

  k_ln<<<NB * NN, 256, 0, stream>>>(a_i, s_i, ada_ln2_w, aln, sln);
  k_wzprep<<<1, 256, 0, stream>>>(lnz_w, lnz_b, Wz, Wzp, TK);
  k_adaln<<<dim3(CC / 64, NB * NN / 64), 256, 0, stream>>>(
      sln, aln, ada_Wl, ada_bl, ada_Wnb, acond);
  k_pairbias<<<NB * NN * (NN / 128), 256, 0, stream>>>(
      z_ij, beta, Wzp, TK, biasb);
  k_qkvg<<<dim3(CC / 64, NB * NN / 64, 4), 256, 0, stream>>>(
      acond, Wq, bq, Wk, Wv, Wg, qb, kb, vb, gb);
  k_attn<<<NB * NH * (NN / 32), 256, 0, stream>>>(qb, kb, vb, gb, biasb, gob);
  k_out<<<dim3(CC / 64, NB * NN / 64), 256, 0, stream>>>(
      gob, Wo, s_i, Wgs, bgs, out);
}

// Round 5
// 740.532 us; speedup vs baseline: 1.2458x; 1.0980x over previous
//
#include <hip/hip_runtime.h>
#include <hip/hip_bf16.h>

// Problem dims (hardcoded): B=2, N=512, C=768, H=16, D=48, CS=384, CZ=128
#define NB 2
#define NN 512
#define CC 768
#define NH 16
#define DD 48
#define CS 384
#define CZ 128

__device__ inline float2 wave_reduce_sum2(float s, float q) {
  #pragma unroll
  for (int off = 32; off > 0; off >>= 1) {
    s += __shfl_xor(s, off);
    q += __shfl_xor(q, off);
  }
  return make_float2(s, q);
}

__device__ inline float sigmoidf_(float x) { return 1.f / (1.f + __expf(-x)); }

// ---------------------------------------------------------------------------
// K1: LN(a_i) -> aln (no affine), LN(s_i)*w -> sln (weight only)
// grid = B*N = 1024 blocks, 256 threads
// ---------------------------------------------------------------------------
__global__ __launch_bounds__(256) void k_ln(
    const float* __restrict__ a_i, const float* __restrict__ s_i,
    const float* __restrict__ ln2w,
    float* __restrict__ aln, float* __restrict__ sln) {
  int r = blockIdx.x, t = threadIdx.x;
  int lane = t & 63, w = t >> 6;
  __shared__ float red[2][4];

  // ---- a row (768) ----
  const float* ar = a_i + (size_t)r * CC;
  float x0 = ar[t], x1 = ar[t + 256], x2 = ar[t + 512];
  float s = x0 + x1 + x2, sq = x0 * x0 + x1 * x1 + x2 * x2;
  float2 rs = wave_reduce_sum2(s, sq);
  if (lane == 0) { red[0][w] = rs.x; red[1][w] = rs.y; }
  __syncthreads();
  float S = red[0][0] + red[0][1] + red[0][2] + red[0][3];
  float SQ = red[1][0] + red[1][1] + red[1][2] + red[1][3];
  float mean = S * (1.f / CC);
  float var = SQ * (1.f / CC) - mean * mean;
  float rstd = rsqrtf(var + 1e-5f);
  float* alr = aln + (size_t)r * CC;
  alr[t] = (x0 - mean) * rstd;
  alr[t + 256] = (x1 - mean) * rstd;
  alr[t + 512] = (x2 - mean) * rstd;

  // ---- s row (384) ----
  const float* sr = s_i + (size_t)r * CS;
  float y0 = sr[t];
  float y1 = (t < 128) ? sr[256 + t] : 0.f;
  float s2 = y0 + y1, sq2 = y0 * y0 + y1 * y1;
  float2 rs2 = wave_reduce_sum2(s2, sq2);
  __syncthreads();  // protect red[] reads above
  if (lane == 0) { red[0][w] = rs2.x; red[1][w] = rs2.y; }
  __syncthreads();
  float S2 = red[0][0] + red[0][1] + red[0][2] + red[0][3];
  float SQ2 = red[1][0] + red[1][1] + red[1][2] + red[1][3];
  float mean2 = S2 * (1.f / CS);
  float var2 = SQ2 * (1.f / CS) - mean2 * mean2;
  float rstd2 = rsqrtf(var2 + 1e-5f);
  float* slr = sln + (size_t)r * CS;
  slr[t] = (y0 - mean2) * rstd2 * ln2w[t];
  if (t < 128) slr[256 + t] = (y1 - mean2) * rstd2 * ln2w[256 + t];
}

// ---------------------------------------------------------------------------
// K2: acond = sigmoid(sln@Wl^T + bl) * aln + sln@Wnb^T
// M=1024, N=768, K=384. 32x64 tile, 2x4 micro, 256 thr.
// grid (12, 32) = 384 blocks (was 192 -> half the GPU idle).
// ---------------------------------------------------------------------------
__global__ __launch_bounds__(256) void k_adaln(
    const float* __restrict__ sln, const float* __restrict__ aln,
    const float* __restrict__ Wl, const float* __restrict__ bl,
    const float* __restrict__ Wnb, float* __restrict__ acond) {
  __shared__ __align__(16) float As[16][36], B1[16][68], B2[16][68];
  int cb = blockIdx.x * 64, rb = blockIdx.y * 32;
  int t = threadIdx.x, tr = t >> 4, tc = t & 15;
  int lk = t & 15, lr = t >> 4;
  float acc1[2][4] = {}, acc2[2][4] = {};
  for (int kb = 0; kb < CS; kb += 16) {
    #pragma unroll
    for (int i = 0; i < 2; ++i) {
      int row = lr + i * 16;
      As[lk][row] = sln[(size_t)(rb + row) * CS + kb + lk];
    }
    #pragma unroll
    for (int i = 0; i < 4; ++i) {
      int row = lr + i * 16;
      B1[lk][row] = Wl[(size_t)(cb + row) * CS + kb + lk];
      B2[lk][row] = Wnb[(size_t)(cb + row) * CS + kb + lk];
    }
    __syncthreads();
    #pragma unroll
    for (int k = 0; k < 16; ++k) {
      float2 av = ((const float2*)&As[k][0])[tr];
      float4 b1v = ((const float4*)&B1[k][0])[tc];
      float4 b2v = ((const float4*)&B2[k][0])[tc];
      float a[2] = {av.x, av.y};
      float b1a[4] = {b1v.x, b1v.y, b1v.z, b1v.w};
      float b2a[4] = {b2v.x, b2v.y, b2v.z, b2v.w};
      #pragma unroll
      for (int i = 0; i < 2; ++i)
        #pragma unroll
        for (int j = 0; j < 4; ++j) {
          acc1[i][j] += a[i] * b1a[j];
          acc2[i][j] += a[i] * b2a[j];
        }
    }
    __syncthreads();
  }
  #pragma unroll
  for (int i = 0; i < 2; ++i) {
    int r = rb + tr * 2 + i;
    #pragma unroll
    for (int j = 0; j < 4; ++j) {
      int c = cb + tc * 4 + j;
      float sig = sigmoidf_(acc1[i][j] + bl[c]);
      acond[(size_t)r * CC + c] = sig * aln[(size_t)r * CC + c] + acc2[i][j];
    }
  }
}

// ---------------------------------------------------------------------------
// K3: fused QKVG, one output matrix per blockIdx.z.
// q=(acond@Wq^T+bq)/sqrt(D), k, v, g=sigmoid(acond@Wg^T)
// M=1024, N=768, K=768. grid (12,16,4), 256 thr, 64x64 tile, float4 LDS reads.
// ---------------------------------------------------------------------------
__global__ __launch_bounds__(256) void k_qkvg(
    const float* __restrict__ acond,
    const float* __restrict__ Wq, const float* __restrict__ bq,
    const float* __restrict__ Wk, const float* __restrict__ Wv,
    const float* __restrict__ Wg,
    float* __restrict__ qo, float* __restrict__ ko,
    float* __restrict__ vo, float* __restrict__ go) {
  __shared__ __align__(16) float As[16][68], Bs[16][68];
  int zid = blockIdx.z;
  const float* W = (zid == 0) ? Wq : (zid == 1) ? Wk : (zid == 2) ? Wv : Wg;
  int cb = blockIdx.x * 64, rb = blockIdx.y * 64;
  int t = threadIdx.x, tr = t >> 4, tc = t & 15;
  int lk = t & 15, lr = t >> 4;
  float acc[4][4] = {};
  for (int kb = 0; kb < CC; kb += 16) {
    #pragma unroll
    for (int i = 0; i < 4; ++i) {
      int row = lr + i * 16;
      As[lk][row] = acond[(size_t)(rb + row) * CC + kb + lk];
      Bs[lk][row] = W[(size_t)(cb + row) * CC + kb + lk];
    }
    __syncthreads();
    #pragma unroll
    for (int k = 0; k < 16; ++k) {
      float4 av = ((const float4*)&As[k][0])[tr];
      float4 bv = ((const float4*)&Bs[k][0])[tc];
      float a[4] = {av.x, av.y, av.z, av.w};
      float bb[4] = {bv.x, bv.y, bv.z, bv.w};
      #pragma unroll
      for (int i = 0; i < 4; ++i)
        #pragma unroll
        for (int j = 0; j < 4; ++j) acc[i][j] += a[i] * bb[j];
    }
    __syncthreads();
  }
  const float qscale = 0.14433756729740643f;  // 1/sqrt(48)
  #pragma unroll
  for (int i = 0; i < 4; ++i) {
    int r = rb + tr * 4 + i;
    #pragma unroll
    for (int j = 0; j < 4; ++j) {
      int c = cb + tc * 4 + j;
      size_t o = (size_t)r * CC + c;
      if (zid == 0)      qo[o] = (acc[i][j] + bq[c]) * qscale;
      else if (zid == 1) ko[o] = acc[i][j];
      else if (zid == 2) vo[o] = acc[i][j];
      else               go[o] = sigmoidf_(acc[i][j]);
    }
  }
}

// ---------------------------------------------------------------------------
// K4a: precompute Wzp[h][c] = lnzw[c]*Wz[h][c];  TK[h]=sum_c Wzp[h][c];
//      TK[16+h] = sum_c lnzb[c]*Wz[h][c].  1 block, 256 thr.
// ---------------------------------------------------------------------------
__global__ __launch_bounds__(256) void k_wzprep(
    const float* __restrict__ lnzw, const float* __restrict__ lnzb,
    const float* __restrict__ Wz, float* __restrict__ Wzp,
    float* __restrict__ TK) {
  int t = threadIdx.x;
  for (int idx = t; idx < NH * CZ; idx += 256)
    Wzp[idx] = lnzw[idx & (CZ - 1)] * Wz[idx];
  if (t < 32) {
    int h = t & 15;
    const float* wr = Wz + (size_t)h * CZ;
    const float* coef = (t < 16) ? lnzw : lnzb;
    float acc = 0.f;
    for (int c = 0; c < CZ; ++c) acc += coef[c] * wr[c];
    TK[(t < 16) ? h : 16 + h] = acc;
  }
}

// ---------------------------------------------------------------------------
// K4b: pair bias via LN-linearity: out[h] = rstd*(S_h - mean*T_h) + Kb_h + beta
// LDS-staged: global->LDS in flat coalesced order (wave instr = 8 rows x 128B
// contiguous segments), XOR-swizzled 16B slots (read phase = 8 lane-groups
// each covering all 32 banks -> data-minimum phases, no excess conflict),
// then thread t owns row t -> Wzp index is wave-UNIFORM -> s_load / SGPR
// operands (zero per-lane Wzp bandwidth, low VGPR). 4 col-chunks of 32c.
// grid = B*N*(N/256) = 2048 blocks, 256 thr.
// ---------------------------------------------------------------------------
__global__ __launch_bounds__(256) void k_pairbias(
    const float* __restrict__ z, const float* __restrict__ beta,
    const float* __restrict__ Wzp, const float* __restrict__ TK,
    float* __restrict__ bias) {
  __shared__ __align__(16) float zs[256 * 32];  // 32 KB
  int blk = blockIdx.x;
  int jh = blk & 1, i = (blk >> 1) & (NN - 1), b = blk >> 10;
  int t = threadIdx.x;
  int j = jh * 256 + t;

  const float* zbase = z + ((size_t)(b * NN + i) * NN + jh * 256) * CZ;
  const float4* Wzp4 = (const float4*)Wzp;
  float S[16];
  #pragma unroll
  for (int h = 0; h < 16; ++h) S[h] = 0.f;
  float sum = 0.f, sq = 0.f;

  int srow = t >> 3;  // staging: row offset within each 32-row group
  int ss = t & 7;     // staging: 16B slot within the 32-float chunk

  for (int ch = 0; ch < 4; ++ch) {
    __syncthreads();  // protect previous chunk's reads
    #pragma unroll
    for (int p = 0; p < 8; ++p) {
      int r = p * 32 + srow;
      float4 v = *(const float4*)(zbase + (size_t)r * CZ + ch * 32 + ss * 4);
      *(float4*)&zs[r * 32 + ((ss ^ (r & 7)) << 2)] = v;
    }
    __syncthreads();
    #pragma unroll
    for (int s = 0; s < 8; ++s) {
      float4 zv = *(const float4*)&zs[t * 32 + ((s ^ (t & 7)) << 2)];
      sum += (zv.x + zv.y) + (zv.z + zv.w);
      sq += zv.x * zv.x + zv.y * zv.y + zv.z * zv.z + zv.w * zv.w;
      #pragma unroll
      for (int h = 0; h < 16; ++h) {
        float4 wv = Wzp4[h * 32 + ch * 8 + s];  // uniform -> SGPR
        S[h] += zv.x * wv.x + zv.y * wv.y + zv.z * wv.z + zv.w * wv.w;
      }
    }
  }
  float mean = sum * (1.f / CZ);
  float var = fmaxf(sq * (1.f / CZ) - mean * mean, 0.f);
  float rstd = rsqrtf(var + 1e-5f);
  float bet = beta[((size_t)(b * NN + i)) * NN + j];
  size_t obase = (((size_t)b * NH) * NN + i) * NN + j;
  #pragma unroll
  for (int h = 0; h < 16; ++h) {
    bias[obase + (size_t)h * NN * NN] =
        rstd * (S[h] - mean * TK[h]) + TK[16 + h] + bet;
  }
}

// ---------------------------------------------------------------------------
// K5: flash attention + g-gating. block per (b,h,32-row q tile). 256 thr.
// Wave-parallel online softmax: 8 lanes per score row.
// ---------------------------------------------------------------------------
__global__ __launch_bounds__(256) void k_attn(
    const float* __restrict__ q, const float* __restrict__ k,
    const float* __restrict__ v, const float* __restrict__ g,
    const float* __restrict__ bias, float* __restrict__ go_out) {
  __shared__ __align__(16) float qs[32][49];
  __shared__ __align__(16) float ks[64][49];
  __shared__ __align__(16) float vs[64][49];
  __shared__ __align__(16) float ps[32][65];
  __shared__ __align__(16) float bs[32][65];
  __shared__ float mrow[32], lrow[32], crow[32];
  int blk = blockIdx.x;
  int it = blk & 15, h = (blk >> 4) & 15, b = blk >> 8;
  int ibase = it * 32;
  int t = threadIdx.x;
  int tr = t >> 4, tc = t & 15;  // scores: qi=tr*2+i, ji=tc*4+j
  int td = t & 15;               // pv: qi=tr*2+i, d=td*3+dd
  int sr = t >> 3, sl = t & 7;   // softmax: row sr, 8 lanes per row

  for (int idx = t; idx < 32 * 48; idx += 256) {
    int r = idx / 48, c = idx % 48;
    qs[r][c] = q[((size_t)(b * NN) + ibase + r) * CC + h * DD + c];
  }
  if (t < 32) { mrow[t] = -1e30f; lrow[t] = 0.f; }
  float acc[2][3] = {};
  const size_t bh = (size_t)b * NH + h;

  for (int jb = 0; jb < NN; jb += 64) {
    __syncthreads();
    for (int idx = t; idx < 64 * 48; idx += 256) {
      int r = idx / 48, c = idx % 48;
      size_t src = ((size_t)(b * NN) + jb + r) * CC + h * DD + c;
      ks[r][c] = k[src];
      vs[r][c] = v[src];
    }
    for (int idx = t; idx < 32 * 64; idx += 256) {
      int r = idx >> 6, c = idx & 63;
      bs[r][c] = bias[(bh * NN + ibase + r) * NN + jb + c];
    }
    __syncthreads();
    // scores
    float sc[2][4] = {};
    #pragma unroll
    for (int d = 0; d < DD; ++d) {
      float a0 = qs[tr * 2][d], a1 = qs[tr * 2 + 1][d];
      #pragma unroll
      for (int j = 0; j < 4; ++j) {
        float bk = ks[tc * 4 + j][d];
        sc[0][j] += a0 * bk;
        sc[1][j] += a1 * bk;
      }
    }
    #pragma unroll
    for (int i = 0; i < 2; ++i)
      #pragma unroll
      for (int j = 0; j < 4; ++j)
        ps[tr * 2 + i][tc * 4 + j] = sc[i][j] + bs[tr * 2 + i][tc * 4 + j];
    __syncthreads();
    // wave-parallel online softmax: 8 lanes per row, shfl_xor over 1,2,4
    {
      float lm = -1e30f;
      #pragma unroll
      for (int jj = 0; jj < 8; ++jj) lm = fmaxf(lm, ps[sr][sl * 8 + jj]);
      lm = fmaxf(lm, __shfl_xor(lm, 1));
      lm = fmaxf(lm, __shfl_xor(lm, 2));
      lm = fmaxf(lm, __shfl_xor(lm, 4));
      float m_old = mrow[sr];
      float rmax = fmaxf(m_old, lm);
      float lsum = 0.f;
      #pragma unroll
      for (int jj = 0; jj < 8; ++jj) {
        float p = __expf(ps[sr][sl * 8 + jj] - rmax);
        ps[sr][sl * 8 + jj] = p;
        lsum += p;
      }
      lsum += __shfl_xor(lsum, 1);
      lsum += __shfl_xor(lsum, 2);
      lsum += __shfl_xor(lsum, 4);
      if (sl == 0) {
        float corr = __expf(m_old - rmax);
        lrow[sr] = lrow[sr] * corr + lsum;
        mrow[sr] = rmax;
        crow[sr] = corr;
      }
    }
    __syncthreads();
    // PV
    float c0 = crow[tr * 2], c1 = crow[tr * 2 + 1];
    #pragma unroll
    for (int dd = 0; dd < 3; ++dd) { acc[0][dd] *= c0; acc[1][dd] *= c1; }
    #pragma unroll
    for (int ji = 0; ji < 64; ++ji) {
      float p0 = ps[tr * 2][ji], p1 = ps[tr * 2 + 1][ji];
      #pragma unroll
      for (int dd = 0; dd < 3; ++dd) {
        float vv = vs[ji][td * 3 + dd];
        acc[0][dd] += p0 * vv;
        acc[1][dd] += p1 * vv;
      }
    }
  }
  __syncthreads();
  #pragma unroll
  for (int i = 0; i < 2; ++i) {
    int qi = tr * 2 + i;
    float inv = 1.f / lrow[qi];
    #pragma unroll
    for (int dd = 0; dd < 3; ++dd) {
      int d = td * 3 + dd;
      size_t o = ((size_t)(b * NN) + ibase + qi) * CC + h * DD + d;
      go_out[o] = acc[i][dd] * inv * g[o];
    }
  }
}

// ---------------------------------------------------------------------------
// K6: out = sigmoid(s_i@Wgs^T + bgs) * (go@Wo^T)
// 32x64 tile, 2x4 micro, 256 thr. grid (12, 32) = 384 blocks.
// ---------------------------------------------------------------------------
__global__ __launch_bounds__(256) void k_out(
    const float* __restrict__ go, const float* __restrict__ Wo,
    const float* __restrict__ s_i, const float* __restrict__ Wgs,
    const float* __restrict__ bgs, float* __restrict__ out) {
  __shared__ __align__(16) float As[16][36], Bs[16][68];
  int cb = blockIdx.x * 64, rb = blockIdx.y * 32;
  int t = threadIdx.x, tr = t >> 4, tc = t & 15;
  int lk = t & 15, lr = t >> 4;
  float acc1[2][4] = {}, acc2[2][4] = {};
  for (int kb = 0; kb < CC; kb += 16) {
    #pragma unroll
    for (int i = 0; i < 2; ++i) {
      int row = lr + i * 16;
      As[lk][row] = go[(size_t)(rb + row) * CC + kb + lk];
    }
    #pragma unroll
    for (int i = 0; i < 4; ++i) {
      int row = lr + i * 16;
      Bs[lk][row] = Wo[(size_t)(cb + row) * CC + kb + lk];
    }
    __syncthreads();
    #pragma unroll
    for (int k = 0; k < 16; ++k) {
      float2 av = ((const float2*)&As[k][0])[tr];
      float4 bv = ((const float4*)&Bs[k][0])[tc];
      float a[2] = {av.x, av.y};
      float bb[4] = {bv.x, bv.y, bv.z, bv.w};
      #pragma unroll
      for (int i = 0; i < 2; ++i)
        #pragma unroll
        for (int j = 0; j < 4; ++j) acc1[i][j] += a[i] * bb[j];
    }
    __syncthreads();
  }
  for (int kb = 0; kb < CS; kb += 16) {
    #pragma unroll
    for (int i = 0; i < 2; ++i) {
      int row = lr + i * 16;
      As[lk][row] = s_i[(size_t)(rb + row) * CS + kb + lk];
    }
    #pragma unroll
    for (int i = 0; i < 4; ++i) {
      int row = lr + i * 16;
      Bs[lk][row] = Wgs[(size_t)(cb + row) * CS + kb + lk];
    }
    __syncthreads();
    #pragma unroll
    for (int k = 0; k < 16; ++k) {
      float2 av = ((const float2*)&As[k][0])[tr];
      float4 bv = ((const float4*)&Bs[k][0])[tc];
      float a[2] = {av.x, av.y};
      float bb[4] = {bv.x, bv.y, bv.z, bv.w};
      #pragma unroll
      for (int i = 0; i < 2; ++i)
        #pragma unroll
        for (int j = 0; j < 4; ++j) acc2[i][j] += a[i] * bb[j];
    }
    __syncthreads();
  }
  #pragma unroll
  for (int i = 0; i < 2; ++i) {
    int r = rb + tr * 2 + i;
    #pragma unroll
    for (int j = 0; j < 4; ++j) {
      int c = cb + tc * 4 + j;
      float gate = sigmoidf_(acc2[i][j] + bgs[c]);
      out[(size_t)r * CC + c] = gate * acc1[i][j];
    }
  }
}

extern "C" void kernel_launch(void* const* d_in, const int* in_sizes, int n_in,
                              void* d_out, int out_size, void* d_ws, size_t ws_size,
                              hipStream_t stream) {
  const float* a_i  = (const float*)d_in[0];
  const float* s_i  = (const float*)d_in[1];
  const float* z_ij = (const float*)d_in[2];
  const float* beta = (const float*)d_in[3];
  const float* Wq   = (const float*)d_in[4];
  const float* bq   = (const float*)d_in[5];
  const float* Wk   = (const float*)d_in[6];
  const float* Wv   = (const float*)d_in[7];
  const float* Wg   = (const float*)d_in[8];
  const float* Wo   = (const float*)d_in[9];
  const float* ada_ln2_w = (const float*)d_in[10];
  const float* ada_Wl = (const float*)d_in[11];
  const float* ada_bl = (const float*)d_in[12];
  const float* ada_Wnb = (const float*)d_in[13];
  const float* lnz_w = (const float*)d_in[14];
  const float* lnz_b = (const float*)d_in[15];
  const float* Wz  = (const float*)d_in[16];
  const float* Wgs = (const float*)d_in[17];
  const float* bgs = (const float*)d_in[18];
  float* out = (float*)d_out;

  float* ws = (float*)d_ws;
  const size_t RC = (size_t)NB * NN * CC;   // 786432
  const size_t RS = (size_t)NB * NN * CS;   // 393216
  float* aln   = ws;
  float* sln   = aln + RC;
  float* acond = sln + RS;
  float* qb    = acond + RC;
  float* kb    = qb + RC;
  float* vb    = kb + RC;
  float* gb    = vb + RC;
  float* gob   = gb + RC;
  float* biasb = gob + RC;                  // B*H*N*N = 8388608 floats
  float* Wzp   = biasb + (size_t)NB * NH * NN * NN;  // 2048
  float* TK    = Wzp + NH * CZ;                      // 32

  k_ln<<<NB * NN, 256, 0, stream>>>(a_i, s_i, ada_ln2_w, aln, sln);
  k_wzprep<<<1, 256, 0, stream>>>(lnz_w, lnz_b, Wz, Wzp, TK);
  k_adaln<<<dim3(CC / 64, NB * NN / 32), 256, 0, stream>>>(
      sln, aln, ada_Wl, ada_bl, ada_Wnb, acond);
  k_pairbias<<<NB * NN * (NN / 256), 256, 0, stream>>>(
      z_ij, beta, Wzp, TK, biasb);
  k_qkvg<<<dim3(CC / 64, NB * NN / 64, 4), 256, 0, stream>>>(
      acond, Wq, bq, Wk, Wv, Wg, qb, kb, vb, gb);
  k_attn<<<NB * NH * (NN / 32), 256, 0, stream>>>(qb, kb, vb, gb, biasb, gob);
  k_out<<<dim3(CC / 64, NB * NN / 32), 256, 0, stream>>>(
      gob, Wo, s_i, Wgs, bgs, out);
}

// Round 6
// 681.599 us; speedup vs baseline: 1.3536x; 1.0865x over previous
//
#include <hip/hip_runtime.h>
#include <hip/hip_bf16.h>

// Problem dims (hardcoded): B=2, N=512, C=768, H=16, D=48, CS=384, CZ=128
#define NB 2
#define NN 512
#define CC 768
#define NH 16
#define DD 48
#define CS 384
#define CZ 128

__device__ inline float2 wave_reduce_sum2(float s, float q) {
  #pragma unroll
  for (int off = 32; off > 0; off >>= 1) {
    s += __shfl_xor(s, off);
    q += __shfl_xor(q, off);
  }
  return make_float2(s, q);
}

__device__ inline float sigmoidf_(float x) { return 1.f / (1.f + __expf(-x)); }

// ---------------------------------------------------------------------------
// K1: LN(a_i) -> aln (no affine), LN(s_i)*w -> sln (weight only)
// grid = B*N = 1024 blocks, 256 threads
// ---------------------------------------------------------------------------
__global__ __launch_bounds__(256) void k_ln(
    const float* __restrict__ a_i, const float* __restrict__ s_i,
    const float* __restrict__ ln2w,
    float* __restrict__ aln, float* __restrict__ sln) {
  int r = blockIdx.x, t = threadIdx.x;
  int lane = t & 63, w = t >> 6;
  __shared__ float red[2][4];

  // ---- a row (768) ----
  const float* ar = a_i + (size_t)r * CC;
  float x0 = ar[t], x1 = ar[t + 256], x2 = ar[t + 512];
  float s = x0 + x1 + x2, sq = x0 * x0 + x1 * x1 + x2 * x2;
  float2 rs = wave_reduce_sum2(s, sq);
  if (lane == 0) { red[0][w] = rs.x; red[1][w] = rs.y; }
  __syncthreads();
  float S = red[0][0] + red[0][1] + red[0][2] + red[0][3];
  float SQ = red[1][0] + red[1][1] + red[1][2] + red[1][3];
  float mean = S * (1.f / CC);
  float var = SQ * (1.f / CC) - mean * mean;
  float rstd = rsqrtf(var + 1e-5f);
  float* alr = aln + (size_t)r * CC;
  alr[t] = (x0 - mean) * rstd;
  alr[t + 256] = (x1 - mean) * rstd;
  alr[t + 512] = (x2 - mean) * rstd;

  // ---- s row (384) ----
  const float* sr = s_i + (size_t)r * CS;
  float y0 = sr[t];
  float y1 = (t < 128) ? sr[256 + t] : 0.f;
  float s2 = y0 + y1, sq2 = y0 * y0 + y1 * y1;
  float2 rs2 = wave_reduce_sum2(s2, sq2);
  __syncthreads();  // protect red[] reads above
  if (lane == 0) { red[0][w] = rs2.x; red[1][w] = rs2.y; }
  __syncthreads();
  float S2 = red[0][0] + red[0][1] + red[0][2] + red[0][3];
  float SQ2 = red[1][0] + red[1][1] + red[1][2] + red[1][3];
  float mean2 = S2 * (1.f / CS);
  float var2 = SQ2 * (1.f / CS) - mean2 * mean2;
  float rstd2 = rsqrtf(var2 + 1e-5f);
  float* slr = sln + (size_t)r * CS;
  slr[t] = (y0 - mean2) * rstd2 * ln2w[t];
  if (t < 128) slr[256 + t] = (y1 - mean2) * rstd2 * ln2w[256 + t];
}

// ---------------------------------------------------------------------------
// K2: acond = sigmoid(sln@Wl^T + bl) * aln + sln@Wnb^T
// M=1024, N=768, K=384. 32x64 tile, 2x4 micro, 256 thr. grid (12,32).
// ---------------------------------------------------------------------------
__global__ __launch_bounds__(256) void k_adaln(
    const float* __restrict__ sln, const float* __restrict__ aln,
    const float* __restrict__ Wl, const float* __restrict__ bl,
    const float* __restrict__ Wnb, float* __restrict__ acond) {
  __shared__ __align__(16) float As[16][36], B1[16][68], B2[16][68];
  int cb = blockIdx.x * 64, rb = blockIdx.y * 32;
  int t = threadIdx.x, tr = t >> 4, tc = t & 15;
  int lk = t & 15, lr = t >> 4;
  float acc1[2][4] = {}, acc2[2][4] = {};
  for (int kb = 0; kb < CS; kb += 16) {
    #pragma unroll
    for (int i = 0; i < 2; ++i) {
      int row = lr + i * 16;
      As[lk][row] = sln[(size_t)(rb + row) * CS + kb + lk];
    }
    #pragma unroll
    for (int i = 0; i < 4; ++i) {
      int row = lr + i * 16;
      B1[lk][row] = Wl[(size_t)(cb + row) * CS + kb + lk];
      B2[lk][row] = Wnb[(size_t)(cb + row) * CS + kb + lk];
    }
    __syncthreads();
    #pragma unroll
    for (int k = 0; k < 16; ++k) {
      float2 av = ((const float2*)&As[k][0])[tr];
      float4 b1v = ((const float4*)&B1[k][0])[tc];
      float4 b2v = ((const float4*)&B2[k][0])[tc];
      float a[2] = {av.x, av.y};
      float b1a[4] = {b1v.x, b1v.y, b1v.z, b1v.w};
      float b2a[4] = {b2v.x, b2v.y, b2v.z, b2v.w};
      #pragma unroll
      for (int i = 0; i < 2; ++i)
        #pragma unroll
        for (int j = 0; j < 4; ++j) {
          acc1[i][j] += a[i] * b1a[j];
          acc2[i][j] += a[i] * b2a[j];
        }
    }
    __syncthreads();
  }
  #pragma unroll
  for (int i = 0; i < 2; ++i) {
    int r = rb + tr * 2 + i;
    #pragma unroll
    for (int j = 0; j < 4; ++j) {
      int c = cb + tc * 4 + j;
      float sig = sigmoidf_(acc1[i][j] + bl[c]);
      acond[(size_t)r * CC + c] = sig * aln[(size_t)r * CC + c] + acc2[i][j];
    }
  }
}

// ---------------------------------------------------------------------------
// K3: fused QKVG, one output matrix per blockIdx.z.
// q=(acond@Wq^T+bq)/sqrt(D), k, v, g=sigmoid(acond@Wg^T)
// M=1024, N=768, K=768. grid (12,16,4), 256 thr, 64x64 tile, float4 LDS reads.
// ---------------------------------------------------------------------------
__global__ __launch_bounds__(256) void k_qkvg(
    const float* __restrict__ acond,
    const float* __restrict__ Wq, const float* __restrict__ bq,
    const float* __restrict__ Wk, const float* __restrict__ Wv,
    const float* __restrict__ Wg,
    float* __restrict__ qo, float* __restrict__ ko,
    float* __restrict__ vo, float* __restrict__ go) {
  __shared__ __align__(16) float As[16][68], Bs[16][68];
  int zid = blockIdx.z;
  const float* W = (zid == 0) ? Wq : (zid == 1) ? Wk : (zid == 2) ? Wv : Wg;
  int cb = blockIdx.x * 64, rb = blockIdx.y * 64;
  int t = threadIdx.x, tr = t >> 4, tc = t & 15;
  int lk = t & 15, lr = t >> 4;
  float acc[4][4] = {};
  for (int kb = 0; kb < CC; kb += 16) {
    #pragma unroll
    for (int i = 0; i < 4; ++i) {
      int row = lr + i * 16;
      As[lk][row] = acond[(size_t)(rb + row) * CC + kb + lk];
      Bs[lk][row] = W[(size_t)(cb + row) * CC + kb + lk];
    }
    __syncthreads();
    #pragma unroll
    for (int k = 0; k < 16; ++k) {
      float4 av = ((const float4*)&As[k][0])[tr];
      float4 bv = ((const float4*)&Bs[k][0])[tc];
      float a[4] = {av.x, av.y, av.z, av.w};
      float bb[4] = {bv.x, bv.y, bv.z, bv.w};
      #pragma unroll
      for (int i = 0; i < 4; ++i)
        #pragma unroll
        for (int j = 0; j < 4; ++j) acc[i][j] += a[i] * bb[j];
    }
    __syncthreads();
  }
  const float qscale = 0.14433756729740643f;  // 1/sqrt(48)
  #pragma unroll
  for (int i = 0; i < 4; ++i) {
    int r = rb + tr * 4 + i;
    #pragma unroll
    for (int j = 0; j < 4; ++j) {
      int c = cb + tc * 4 + j;
      size_t o = (size_t)r * CC + c;
      if (zid == 0)      qo[o] = (acc[i][j] + bq[c]) * qscale;
      else if (zid == 1) ko[o] = acc[i][j];
      else if (zid == 2) vo[o] = acc[i][j];
      else               go[o] = sigmoidf_(acc[i][j]);
    }
  }
}

// ---------------------------------------------------------------------------
// K4a: precompute Wzp[h][c] = lnzw[c]*Wz[h][c];  TK[h]=sum_c Wzp[h][c];
//      TK[16+h] = sum_c lnzb[c]*Wz[h][c].  1 block, 256 thr.
// ---------------------------------------------------------------------------
__global__ __launch_bounds__(256) void k_wzprep(
    const float* __restrict__ lnzw, const float* __restrict__ lnzb,
    const float* __restrict__ Wz, float* __restrict__ Wzp,
    float* __restrict__ TK) {
  int t = threadIdx.x;
  for (int idx = t; idx < NH * CZ; idx += 256)
    Wzp[idx] = lnzw[idx & (CZ - 1)] * Wz[idx];
  if (t < 32) {
    int h = t & 15;
    const float* wr = Wz + (size_t)h * CZ;
    const float* coef = (t < 16) ? lnzw : lnzb;
    float acc = 0.f;
    for (int c = 0; c < CZ; ++c) acc += coef[c] * wr[c];
    TK[(t < 16) ? h : 16 + h] = acc;
  }
}

// ---------------------------------------------------------------------------
// K4b: pair bias as register-blocked GEMM, ZERO SMEM in the hot loop.
//   out[j,h] = rstd_j*(S[j,h] - mean_j*TK[h]) + TK[16+h] + beta[j]
// Both operands from LDS: ws[c][h] staged once (8KB); zs staged per-32c chunk
// TRANSPOSED [c][row] (pad 260 -> 16B-aligned b128; reads 2-way = free,
// transpose writes 4-way = minor). Thread = 4 rows x 4 heads: per c-step
// 2x ds_read_b128 + 16 FMA (both sides amortized 4x, lgkmcnt in-order).
// LN stats accumulated during staging, shfl-reduced into rowstat LDS.
// grid = B*N*(N/256) = 2048 blocks, 256 thr.
// ---------------------------------------------------------------------------
__global__ __launch_bounds__(256) void k_pairbias(
    const float* __restrict__ z, const float* __restrict__ beta,
    const float* __restrict__ Wzp, const float* __restrict__ TK,
    float* __restrict__ bias) {
  __shared__ __align__(16) float zs[32][260];   // 33.3 KB, transposed chunk
  __shared__ __align__(16) float ws[128][20];   // 10 KB, Wzp^T
  __shared__ float rowstat[256][2];             // per-row sum, sumsq
  __shared__ float tks[32];
  int blk = blockIdx.x;
  int jh = blk & 1, i = (blk >> 1) & (NN - 1), b = blk >> 10;
  int t = threadIdx.x;
  int jbase = jh * 256;

  // one-time: ws[c][h] = Wzp[h][c]; tks = TK
  {
    int h = t >> 4, c0 = (t & 15) * 8;
    float4 w0 = *(const float4*)(Wzp + (size_t)h * CZ + c0);
    float4 w1 = *(const float4*)(Wzp + (size_t)h * CZ + c0 + 4);
    ws[c0 + 0][h] = w0.x; ws[c0 + 1][h] = w0.y;
    ws[c0 + 2][h] = w0.z; ws[c0 + 3][h] = w0.w;
    ws[c0 + 4][h] = w1.x; ws[c0 + 5][h] = w1.y;
    ws[c0 + 6][h] = w1.z; ws[c0 + 7][h] = w1.w;
  }
  if (t < 32) tks[t] = TK[t];

  const float* zb = z + ((size_t)(b * NN + i) * NN + jbase) * CZ;
  int srow = t >> 3;        // staging row-within-group 0..31
  int sc = (t & 7) * 4;     // staging c-slice 0,4,..,28
  int rg = t >> 2;          // compute: row-group 0..63 (4 rows)
  int hg = t & 3;           // compute: head-group 0..3 (4 heads)

  float acc[4][4] = {};
  float ssum[8] = {}, ssq[8] = {};

  for (int ch = 0; ch < 4; ++ch) {
    __syncthreads();  // previous chunk's compute done before restage
    #pragma unroll
    for (int p = 0; p < 8; ++p) {
      int r = p * 32 + srow;
      float4 v = *(const float4*)(zb + (size_t)r * CZ + ch * 32 + sc);
      zs[sc + 0][r] = v.x; zs[sc + 1][r] = v.y;
      zs[sc + 2][r] = v.z; zs[sc + 3][r] = v.w;
      ssum[p] += (v.x + v.y) + (v.z + v.w);
      ssq[p] += v.x * v.x + v.y * v.y + v.z * v.z + v.w * v.w;
    }
    __syncthreads();
    #pragma unroll
    for (int c = 0; c < 32; ++c) {
      float4 zv = *(const float4*)&zs[c][rg * 4];
      float4 wv = *(const float4*)&ws[ch * 32 + c][hg * 4];
      float za[4] = {zv.x, zv.y, zv.z, zv.w};
      float wa[4] = {wv.x, wv.y, wv.z, wv.w};
      #pragma unroll
      for (int ri = 0; ri < 4; ++ri)
        #pragma unroll
        for (int hi = 0; hi < 4; ++hi) acc[ri][hi] += za[ri] * wa[hi];
    }
  }

  // reduce LN stats over the 8 c-slice lanes (consecutive lanes)
  #pragma unroll
  for (int p = 0; p < 8; ++p) {
    ssum[p] += __shfl_xor(ssum[p], 1);
    ssum[p] += __shfl_xor(ssum[p], 2);
    ssum[p] += __shfl_xor(ssum[p], 4);
    ssq[p] += __shfl_xor(ssq[p], 1);
    ssq[p] += __shfl_xor(ssq[p], 2);
    ssq[p] += __shfl_xor(ssq[p], 4);
  }
  if ((t & 7) == 0) {
    #pragma unroll
    for (int p = 0; p < 8; ++p) {
      rowstat[p * 32 + srow][0] = ssum[p];
      rowstat[p * 32 + srow][1] = ssq[p];
    }
  }
  __syncthreads();

  float4 bv = *(const float4*)(beta + ((size_t)(b * NN + i)) * NN + jbase + rg * 4);
  float betv[4] = {bv.x, bv.y, bv.z, bv.w};
  float mean[4], rstd[4];
  #pragma unroll
  for (int ri = 0; ri < 4; ++ri) {
    float s = rowstat[rg * 4 + ri][0], q = rowstat[rg * 4 + ri][1];
    mean[ri] = s * (1.f / CZ);
    float var = fmaxf(q * (1.f / CZ) - mean[ri] * mean[ri], 0.f);
    rstd[ri] = rsqrtf(var + 1e-5f);
  }
  size_t base = (((size_t)b * NH) * NN + i) * NN + jbase + rg * 4;
  #pragma unroll
  for (int hi = 0; hi < 4; ++hi) {
    int h = hg * 4 + hi;
    float tkh = tks[h], tkb = tks[16 + h];
    float4 o;
    o.x = rstd[0] * (acc[0][hi] - mean[0] * tkh) + tkb + betv[0];
    o.y = rstd[1] * (acc[1][hi] - mean[1] * tkh) + tkb + betv[1];
    o.z = rstd[2] * (acc[2][hi] - mean[2] * tkh) + tkb + betv[2];
    o.w = rstd[3] * (acc[3][hi] - mean[3] * tkh) + tkb + betv[3];
    *(float4*)(bias + base + (size_t)h * NN * NN) = o;
  }
}

// ---------------------------------------------------------------------------
// K5: flash attention + g-gating. block per (b,h,32-row q tile). 256 thr.
// Wave-parallel online softmax: 8 lanes per score row.
// ---------------------------------------------------------------------------
__global__ __launch_bounds__(256) void k_attn(
    const float* __restrict__ q, const float* __restrict__ k,
    const float* __restrict__ v, const float* __restrict__ g,
    const float* __restrict__ bias, float* __restrict__ go_out) {
  __shared__ __align__(16) float qs[32][49];
  __shared__ __align__(16) float ks[64][49];
  __shared__ __align__(16) float vs[64][49];
  __shared__ __align__(16) float ps[32][65];
  __shared__ __align__(16) float bs[32][65];
  __shared__ float mrow[32], lrow[32], crow[32];
  int blk = blockIdx.x;
  int it = blk & 15, h = (blk >> 4) & 15, b = blk >> 8;
  int ibase = it * 32;
  int t = threadIdx.x;
  int tr = t >> 4, tc = t & 15;  // scores: qi=tr*2+i, ji=tc*4+j
  int td = t & 15;               // pv: qi=tr*2+i, d=td*3+dd
  int sr = t >> 3, sl = t & 7;   // softmax: row sr, 8 lanes per row

  for (int idx = t; idx < 32 * 48; idx += 256) {
    int r = idx / 48, c = idx % 48;
    qs[r][c] = q[((size_t)(b * NN) + ibase + r) * CC + h * DD + c];
  }
  if (t < 32) { mrow[t] = -1e30f; lrow[t] = 0.f; }
  float acc[2][3] = {};
  const size_t bh = (size_t)b * NH + h;

  for (int jb = 0; jb < NN; jb += 64) {
    __syncthreads();
    for (int idx = t; idx < 64 * 48; idx += 256) {
      int r = idx / 48, c = idx % 48;
      size_t src = ((size_t)(b * NN) + jb + r) * CC + h * DD + c;
      ks[r][c] = k[src];
      vs[r][c] = v[src];
    }
    for (int idx = t; idx < 32 * 64; idx += 256) {
      int r = idx >> 6, c = idx & 63;
      bs[r][c] = bias[(bh * NN + ibase + r) * NN + jb + c];
    }
    __syncthreads();
    // scores
    float sc[2][4] = {};
    #pragma unroll
    for (int d = 0; d < DD; ++d) {
      float a0 = qs[tr * 2][d], a1 = qs[tr * 2 + 1][d];
      #pragma unroll
      for (int j = 0; j < 4; ++j) {
        float bk = ks[tc * 4 + j][d];
        sc[0][j] += a0 * bk;
        sc[1][j] += a1 * bk;
      }
    }
    #pragma unroll
    for (int i = 0; i < 2; ++i)
      #pragma unroll
      for (int j = 0; j < 4; ++j)
        ps[tr * 2 + i][tc * 4 + j] = sc[i][j] + bs[tr * 2 + i][tc * 4 + j];
    __syncthreads();
    // wave-parallel online softmax: 8 lanes per row, shfl_xor over 1,2,4
    {
      float lm = -1e30f;
      #pragma unroll
      for (int jj = 0; jj < 8; ++jj) lm = fmaxf(lm, ps[sr][sl * 8 + jj]);
      lm = fmaxf(lm, __shfl_xor(lm, 1));
      lm = fmaxf(lm, __shfl_xor(lm, 2));
      lm = fmaxf(lm, __shfl_xor(lm, 4));
      float m_old = mrow[sr];
      float rmax = fmaxf(m_old, lm);
      float lsum = 0.f;
      #pragma unroll
      for (int jj = 0; jj < 8; ++jj) {
        float p = __expf(ps[sr][sl * 8 + jj] - rmax);
        ps[sr][sl * 8 + jj] = p;
        lsum += p;
      }
      lsum += __shfl_xor(lsum, 1);
      lsum += __shfl_xor(lsum, 2);
      lsum += __shfl_xor(lsum, 4);
      if (sl == 0) {
        float corr = __expf(m_old - rmax);
        lrow[sr] = lrow[sr] * corr + lsum;
        mrow[sr] = rmax;
        crow[sr] = corr;
      }
    }
    __syncthreads();
    // PV
    float c0 = crow[tr * 2], c1 = crow[tr * 2 + 1];
    #pragma unroll
    for (int dd = 0; dd < 3; ++dd) { acc[0][dd] *= c0; acc[1][dd] *= c1; }
    #pragma unroll
    for (int ji = 0; ji < 64; ++ji) {
      float p0 = ps[tr * 2][ji], p1 = ps[tr * 2 + 1][ji];
      #pragma unroll
      for (int dd = 0; dd < 3; ++dd) {
        float vv = vs[ji][td * 3 + dd];
        acc[0][dd] += p0 * vv;
        acc[1][dd] += p1 * vv;
      }
    }
  }
  __syncthreads();
  #pragma unroll
  for (int i = 0; i < 2; ++i) {
    int qi = tr * 2 + i;
    float inv = 1.f / lrow[qi];
    #pragma unroll
    for (int dd = 0; dd < 3; ++dd) {
      int d = td * 3 + dd;
      size_t o = ((size_t)(b * NN) + ibase + qi) * CC + h * DD + d;
      go_out[o] = acc[i][dd] * inv * g[o];
    }
  }
}

// ---------------------------------------------------------------------------
// K6: out = sigmoid(s_i@Wgs^T + bgs) * (go@Wo^T)
// 32x64 tile, 2x4 micro, 256 thr. grid (12, 32) = 384 blocks.
// ---------------------------------------------------------------------------
__global__ __launch_bounds__(256) void k_out(
    const float* __restrict__ go, const float* __restrict__ Wo,
    const float* __restrict__ s_i, const float* __restrict__ Wgs,
    const float* __restrict__ bgs, float* __restrict__ out) {
  __shared__ __align__(16) float As[16][36], Bs[16][68];
  int cb = blockIdx.x * 64, rb = blockIdx.y * 32;
  int t = threadIdx.x, tr = t >> 4, tc = t & 15;
  int lk = t & 15, lr = t >> 4;
  float acc1[2][4] = {}, acc2[2][4] = {};
  for (int kb = 0; kb < CC; kb += 16) {
    #pragma unroll
    for (int i = 0; i < 2; ++i) {
      int row = lr + i * 16;
      As[lk][row] = go[(size_t)(rb + row) * CC + kb + lk];
    }
    #pragma unroll
    for (int i = 0; i < 4; ++i) {
      int row = lr + i * 16;
      Bs[lk][row] = Wo[(size_t)(cb + row) * CC + kb + lk];
    }
    __syncthreads();
    #pragma unroll
    for (int k = 0; k < 16; ++k) {
      float2 av = ((const float2*)&As[k][0])[tr];
      float4 bv = ((const float4*)&Bs[k][0])[tc];
      float a[2] = {av.x, av.y};
      float bb[4] = {bv.x, bv.y, bv.z, bv.w};
      #pragma unroll
      for (int i = 0; i < 2; ++i)
        #pragma unroll
        for (int j = 0; j < 4; ++j) acc1[i][j] += a[i] * bb[j];
    }
    __syncthreads();
  }
  for (int kb = 0; kb < CS; kb += 16) {
    #pragma unroll
    for (int i = 0; i < 2; ++i) {
      int row = lr + i * 16;
      As[lk][row] = s_i[(size_t)(rb + row) * CS + kb + lk];
    }
    #pragma unroll
    for (int i = 0; i < 4; ++i) {
      int row = lr + i * 16;
      Bs[lk][row] = Wgs[(size_t)(cb + row) * CS + kb + lk];
    }
    __syncthreads();
    #pragma unroll
    for (int k = 0; k < 16; ++k) {
      float2 av = ((const float2*)&As[k][0])[tr];
      float4 bv = ((const float4*)&Bs[k][0])[tc];
      float a[2] = {av.x, av.y};
      float bb[4] = {bv.x, bv.y, bv.z, bv.w};
      #pragma unroll
      for (int i = 0; i < 2; ++i)
        #pragma unroll
        for (int j = 0; j < 4; ++j) acc2[i][j] += a[i] * bb[j];
    }
    __syncthreads();
  }
  #pragma unroll
  for (int i = 0; i < 2; ++i) {
    int r = rb + tr * 2 + i;
    #pragma unroll
    for (int j = 0; j < 4; ++j) {
      int c = cb + tc * 4 + j;
      float gate = sigmoidf_(acc2[i][j] + bgs[c]);
      out[(size_t)r * CC + c] = gate * acc1[i][j];
    }
  }
}

extern "C" void kernel_launch(void* const* d_in, const int* in_sizes, int n_in,
                              void* d_out, int out_size, void* d_ws, size_t ws_size,
                              hipStream_t stream) {
  const float* a_i  = (const float*)d_in[0];
  const float* s_i  = (const float*)d_in[1];
  const float* z_ij = (const float*)d_in[2];
  const float* beta = (const float*)d_in[3];
  const float* Wq   = (const float*)d_in[4];
  const float* bq   = (const float*)d_in[5];
  const float* Wk   = (const float*)d_in[6];
  const float* Wv   = (const float*)d_in[7];
  const float* Wg   = (const float*)d_in[8];
  const float* Wo   = (const float*)d_in[9];
  const float* ada_ln2_w = (const float*)d_in[10];
  const float* ada_Wl = (const float*)d_in[11];
  const float* ada_bl = (const float*)d_in[12];
  const float* ada_Wnb = (const float*)d_in[13];
  const float* lnz_w = (const float*)d_in[14];
  const float* lnz_b = (const float*)d_in[15];
  const float* Wz  = (const float*)d_in[16];
  const float* Wgs = (const float*)d_in[17];
  const float* bgs = (const float*)d_in[18];
  float* out = (float*)d_out;

  float* ws = (float*)d_ws;
  const size_t RC = (size_t)NB * NN * CC;   // 786432
  const size_t RS = (size_t)NB * NN * CS;   // 393216
  float* aln   = ws;
  float* sln   = aln + RC;
  float* acond = sln + RS;
  float* qb    = acond + RC;
  float* kb    = qb + RC;
  float* vb    = kb + RC;
  float* gb    = vb + RC;
  float* gob   = gb + RC;
  float* biasb = gob + RC;                  // B*H*N*N = 8388608 floats
  float* Wzp   = biasb + (size_t)NB * NH * NN * NN;  // 2048
  float* TK    = Wzp + NH * CZ;                      // 32

  k_ln<<<NB * NN, 256, 0, stream>>>(a_i, s_i, ada_ln2_w, aln, sln);
  k_wzprep<<<1, 256, 0, stream>>>(lnz_w, lnz_b, Wz, Wzp, TK);
  k_adaln<<<dim3(CC / 64, NB * NN / 32), 256, 0, stream>>>(
      sln, aln, ada_Wl, ada_bl, ada_Wnb, acond);
  k_pairbias<<<NB * NN * (NN / 256), 256, 0, stream>>>(
      z_ij, beta, Wzp, TK, biasb);
  k_qkvg<<<dim3(CC / 64, NB * NN / 64, 4), 256, 0, stream>>>(
      acond, Wq, bq, Wk, Wv, Wg, qb, kb, vb, gb);
  k_attn<<<NB * NH * (NN / 32), 256, 0, stream>>>(qb, kb, vb, gb, biasb, gob);
  k_out<<<dim3(CC / 64, NB * NN / 32), 256, 0, stream>>>(
      gob, Wo, s_i, Wgs, bgs, out);
}